// Round 6
// baseline (299.068 us; speedup 1.0000x reference)
//
#include <hip/hip_runtime.h>
#include <stdint.h>

typedef unsigned long long ull;

#define NUM_CLASSES 21
#define NFG 20
#define TOPK 200
#define KPRE 256
#define CONF_TH 0.01f
#define NMS_TH 0.45f
#define VAR0 0.1f
#define VAR1 0.2f
#define NVMAX 35                 // ceil(8732/256)
#define BITS_CONF 0x3C23D70Au    // __float_as_uint(0.01f)
#define BITS_ONE1 0x3F800001u    // just above 1.0f (softmax <= 1)
// skewed LDS slot: g, g+64, g+128, g+192 land in different banks
#define BSLOT(g) ((g) + ((g) >> 6))

// Grid-barrier counter. Module-scope device global: zero-initialized at load,
// NEVER reset. Monotonic epoch scheme: each launch's 640 blocks take one
// ticket each; launches serialize, so the counter is a multiple of 640 at
// every launch start and each block's release target is (old/640+1)*640.
// Correct across graph replays, rocprof replay passes, and arbitrary
// poisoning of out / d_ws (round-5 failed because the counter lived in
// out[0]: late arrivals atomicAdd'ed into an already-written final output).
__device__ unsigned int g_bar = 0u;

// Fused single-dispatch kernel (round 0-3 data: the two-dispatch pipeline
// pays ~35 us of dispatch-boundary writeback/invalidate scaling with the
// 22 MB dirty intermediate; cooperative launch is not graph-capturable, so
// the grid sync is manual).
// Co-residency: 24 KB LDS -> 6 blocks/CU capacity (1536) >> 640 blocks,
// so the spin barrier cannot deadlock.
// Phase 0: the 20 class-blocks of image b each softmax a disjoint ~437-row
// slice (register rows, op order identical to the verified kernel =>
// bit-identical probs). Phases A..G: unchanged verified NMS pipeline.
__global__ __launch_bounds__(KPRE) void fused_postproc_kernel(
    const float* __restrict__ conf, const float* __restrict__ loc,
    const float* __restrict__ prior, float* __restrict__ probs,
    float* __restrict__ out, int B, int P) {

    __shared__ ull arr[2 * KPRE];
    __shared__ ull arr2[2 * KPRE];              // double buffer for sort LDS stages
    __shared__ int wsum[2][4];
    __shared__ int s_cnt;
    __shared__ float4 sbox[KPRE + (KPRE >> 6)]; // skewed (BSLOT): no 4-way conflict
    __shared__ float sarea[KPRE + (KPRE >> 6)];
    __shared__ ull smask[KPRE][5];              // padded stride 40B: 2-way (free)
    __shared__ ull kept_mask[4];

    const int t = threadIdx.x;
    const int lane = t & 63;
    const int wid = t >> 6;
    const ull lmask_lt = (1ULL << lane) - 1ULL;

    // XCD-aware swizzle (bijective for B%8==0): all 20 classes of an image on
    // one XCD; phase-0 producers and phase-A consumers of image b share an L2
    // (correctness belt: the device-scope fences below cover a mismatch).
    const int g = blockIdx.x;
    int b, c;
    if ((B & 7) == 0) {
        int k = g >> 3;
        b = ((k / NFG) << 3) + (g & 7);
        c = k - (k / NFG) * NFG;
    } else {
        b = g / NFG;
        c = g - (g / NFG) * NFG;
    }
    const int pair = b * NFG + c;

    // ---- Phase 0: softmax for my slice of image b ----
    {
        const int RPB = (P + NFG - 1) / NFG;    // 437
        const int r0 = c * RPB;
        const int rend = min(r0 + RPB, P);
        for (int p = r0 + t; p < rend; p += KPRE) {
            const float* row = conf + ((size_t)b * P + p) * NUM_CLASSES;
            float x[NUM_CLASSES];
            float mx = row[0];
            x[0] = mx;
#pragma unroll
            for (int j = 1; j < NUM_CLASSES; ++j) { x[j] = row[j]; mx = fmaxf(mx, x[j]); }
            float s = 0.f;
#pragma unroll
            for (int j = 0; j < NUM_CLASSES; ++j) { x[j] = expf(x[j] - mx); s += x[j]; }
            float* dp = probs + ((size_t)b * NFG) * P + p;
#pragma unroll
            for (int c2 = 1; c2 < NUM_CLASSES; ++c2)
                dp[(size_t)(c2 - 1) * P] = x[c2] / s;   // lanes consecutive in p => coalesced
        }
    }

    // ---- Manual grid barrier (monotonic epoch; no reset ever) ----
    {
        const unsigned int nblk = gridDim.x;
        __threadfence();                          // release: probs visible device-wide
        __syncthreads();                          // all waves' stores issued before arrive
        if (t == 0) {
            unsigned int old = atomicAdd(&g_bar, 1u);   // device-scope
            unsigned int target = (old / nblk + 1u) * nblk;
            while (__hip_atomic_load(&g_bar, __ATOMIC_RELAXED,
                                     __HIP_MEMORY_SCOPE_AGENT) < target)
                __builtin_amdgcn_s_sleep(8);
        }
        __syncthreads();
        __threadfence();                          // acquire: see all probs
    }

    const float* sp = probs + (size_t)pair * P;

    // A: scores into registers (coalesced dword loads)
    unsigned int ubits[NVMAX];
#pragma unroll
    for (int i = 0; i < NVMAX; ++i) {
        int p = (i << 8) + t;
        ubits[i] = (p < P) ? __float_as_uint(sp[p]) : 0u;
    }

    // B: WAVE-LOCAL binary search (no barriers, no shfl-reduce). Each wave
    // finds largest T_w with its own count >= 64 via ballot+popc (SALU).
    // Global T = min_w T_w  =>  count_global(>=T) >= 256 and T <= V256,
    // so {x >= T} is an exact superset of the global top-256.
    {
        unsigned int lo = BITS_CONF, hi = BITS_ONE1;
        while (hi - lo > 1u) {
            unsigned int mid = lo + ((hi - lo) >> 1);
            int cc = 0;
#pragma unroll
            for (int i = 0; i < NVMAX; ++i)
                cc += __popcll(__ballot(ubits[i] >= mid));
            if (cc >= KPRE / 4) lo = mid; else hi = mid;
        }
        if (lane == 0) wsum[0][wid] = (int)lo;
    }
    __syncthreads();
    unsigned int T = (unsigned int)min(min(wsum[0][0], wsum[0][1]),
                                       min(wsum[0][2], wsum[0][3]));

    // C: ballot-compaction gather (cap 512) + exact-search fallback if the
    // wave-local threshold over-collects (>512: statistically never).
    int nval;
    for (int attempt = 0;; ++attempt) {
        if (t == 0) s_cnt = 0;
        __syncthreads();
        int wtot = 0;
#pragma unroll
        for (int i = 0; i < NVMAX; ++i) {
            int p = (i << 8) + t;
            bool pred = (p < P) && (ubits[i] >= T);
            wtot += __popcll(__ballot(pred));
        }
        int wbase = 0;
        if (lane == 0) wbase = atomicAdd(&s_cnt, wtot);
        wbase = __shfl(wbase, 0);
        int run = wbase;
#pragma unroll
        for (int i = 0; i < NVMAX; ++i) {
            int p = (i << 8) + t;
            bool pred = (p < P) && (ubits[i] >= T);
            ull bal = __ballot(pred);
            if (pred) {
                int slot = run + __popcll(bal & lmask_lt);
                if (slot < 2 * KPRE)
                    arr[slot] = ((ull)ubits[i] << 32) | (unsigned int)(~p);
            }
            run += __popcll(bal);
        }
        __syncthreads();
        if (s_cnt <= 2 * KPRE || attempt == 1) { nval = min(s_cnt, 2 * KPRE); break; }
        // fallback: exact global search, lo invariant count>=256 holds at T
        unsigned int lo = T, hi = BITS_ONE1;
        int it = 0;
        while (hi - lo > 1u) {
            unsigned int mid = lo + ((hi - lo) >> 1);
            int cc = 0;
#pragma unroll
            for (int i = 0; i < NVMAX; ++i)
                cc += __popcll(__ballot(ubits[i] >= mid));
            if (lane == 0) wsum[it & 1][wid] = cc;
            __syncthreads();
            int totc = wsum[it & 1][0] + wsum[it & 1][1] + wsum[it & 1][2] + wsum[it & 1][3];
            if (totc >= KPRE) lo = mid; else hi = mid;
            ++it;
        }
        T = lo;
    }

    for (int e = t; e < 2 * KPRE; e += KPRE)
        if (e >= nval) arr[e] = 0ULL;
    __syncthreads();

    // D: 512-wide bitonic sort, 2 keys/thread (elem t and t+256), descending.
    // key = (bits<<32)|~idx => value desc, index asc (JAX tie-break).
    // LDS stages double-buffered: one barrier per stage.
    ull k0 = arr[t];
    ull k1 = arr[t + KPRE];
    {
        int lstage = 0;
#pragma unroll
        for (int kk = 2; kk <= 2 * KPRE; kk <<= 1) {
#pragma unroll
            for (int j = kk >> 1; j > 0; j >>= 1) {
                if (j == KPRE) {
                    ull mx = (k0 > k1) ? k0 : k1;
                    ull mn = (k0 > k1) ? k1 : k0;
                    k0 = mx; k1 = mn;
                } else if (j >= 64) {
                    ull* A = (lstage & 1) ? arr : arr2;
                    ++lstage;
                    A[t] = k0; A[t + KPRE] = k1;
                    __syncthreads();
                    ull o0 = A[t ^ j];
                    ull o1 = A[(t + KPRE) ^ j];
                    bool amLow = ((t & j) == 0);
                    bool d0 = ((t & kk) == 0);
                    bool d1 = (((t + KPRE) & kk) == 0);
                    k0 = (d0 == amLow) ? ((k0 > o0) ? k0 : o0) : ((k0 > o0) ? o0 : k0);
                    k1 = (d1 == amLow) ? ((k1 > o1) ? k1 : o1) : ((k1 > o1) ? o1 : k1);
                } else {
                    ull o0 = __shfl_xor(k0, j);
                    ull o1 = __shfl_xor(k1, j);
                    bool amLow = ((t & j) == 0);
                    bool d0 = ((t & kk) == 0);
                    bool d1 = (((t + KPRE) & kk) == 0);
                    k0 = (d0 == amLow) ? ((k0 > o0) ? k0 : o0) : ((k0 > o0) ? o0 : k0);
                    k1 = (d1 == amLow) ? ((k1 > o1) ? k1 : o1) : ((k1 > o1) ? o1 : k1);
                }
            }
        }
    }
    const ull key = k0;    // top-256 sorted descending

    // E: decode candidate t
    float v = __uint_as_float((unsigned int)(key >> 32));
    int idx = (int)(~(unsigned int)(key & 0xFFFFFFFFu));
    if (idx < 0 || idx >= P) { idx = 0; v = 0.f; }

    const float4 lv = *(const float4*)(loc + ((size_t)b * P + idx) * 4);
    const float4 pv = *(const float4*)(prior + (size_t)idx * 4);
    float cx = pv.x + (lv.x * VAR0) * pv.z;
    float cy = pv.y + (lv.y * VAR0) * pv.w;
    float w = pv.z * expf(lv.z * VAR1);
    float h = pv.w * expf(lv.w * VAR1);
    float x1 = cx - w * 0.5f;
    float y1 = cy - h * 0.5f;
    float x2 = x1 + w;
    float y2 = y1 + h;
    float myarea = fmaxf(x2 - x1, 0.f) * fmaxf(y2 - y1, 0.f);

    sbox[BSLOT(t)] = make_float4(x1, y1, x2, y2);
    sarea[BSLOT(t)] = myarea;
    __syncthreads();

    // F1: balanced mask build (640 (row,tile) pairs over 256 threads)
#pragma unroll
    for (int rep = 0; rep < 3; ++rep) {
        int pid = t + (rep << 8);
        if (pid < 640) {
            int r, w2;
            if (pid < 64)       { r = pid;                w2 = 0; }
            else if (pid < 192) { int q = pid - 64;  r = 64  + (q >> 1); w2 = q & 1; }
            else if (pid < 384) { int q = pid - 192; int q3 = q / 3; r = 128 + q3; w2 = q - 3 * q3; }
            else                { int q = pid - 384; r = 192 + (q >> 2); w2 = q & 3; }
            float4 rb = sbox[BSLOT(r)];
            float ra = sarea[BSLOT(r)];
            ull mm = 0ULL;
            for (int i = 0; i < 64; ++i) {
                int gg = (w2 << 6) + i;
                float4 gb = sbox[BSLOT(gg)];
                float lx = fmaxf(gb.x, rb.x), ly = fmaxf(gb.y, rb.y);
                float rx = fminf(gb.z, rb.z), ry = fminf(gb.w, rb.w);
                float iw = fmaxf(rx - lx, 0.f), ih = fmaxf(ry - ly, 0.f);
                float inter = iw * ih;
                float uni = sarea[BSLOT(gg)] + ra - inter;
                bool s = (inter / fmaxf(uni, 1e-9f)) > NMS_TH;
                mm |= ((ull)(s ? 1u : 0u)) << i;
            }
            smask[r][w2] = mm;
        }
    }
    __syncthreads();

    // F2: load row masks; resolve wave-serially, but only over lanes whose
    // suppression row is non-empty (todo) — suppressions are rare for random
    // boxes, so the 64-iter dependent-shfl chain shrinks to ~popc(todo).
    ull m0 = smask[t][0];
    ull m1 = (wid >= 1) ? smask[t][1] : 0ULL;
    ull m2 = (wid >= 2) ? smask[t][2] : 0ULL;
    ull m3 = (wid >= 3) ? smask[t][3] : 0ULL;
    if (wid == 0) m0 &= lmask_lt;
    else if (wid == 1) m1 &= lmask_lt;
    else if (wid == 2) m2 &= lmask_lt;
    else m3 &= lmask_lt;

    int alive = (v > CONF_TH) ? 1 : 0;
    ull mykept = 0ULL;
#pragma unroll
    for (int w2 = 0; w2 < 4; ++w2) {
        if (wid == w2) {
            if (w2 > 0 && (m0 & kept_mask[0])) alive = 0;
            if (w2 > 1 && (m1 & kept_mask[1])) alive = 0;
            if (w2 > 2 && (m2 & kept_mask[2])) alive = 0;
            ull mw = (w2 == 0) ? m0 : (w2 == 1) ? m1 : (w2 == 2) ? m2 : m3;
            ull validb = __ballot(alive != 0);
            ull todo = __ballot((mw & validb) != 0ULL) & validb;
            ull kept = validb & ~todo;
            while (todo) {
                int i = __builtin_ctzll(todo);
                ull row = __shfl(mw, i);
                if ((row & kept) == 0ULL) kept |= (1ULL << i);
                todo &= (todo - 1ULL);
            }
            mykept = kept;
            alive = (int)((kept >> lane) & 1ULL);
            if (lane == 0) kept_mask[w2] = kept;
        }
        __syncthreads();
    }

    // G: rank via popcounts, write kept rows + zero-fill
    int rank = 0;
#pragma unroll
    for (int w2 = 0; w2 < 4; ++w2)
        if (w2 < wid) rank += __popcll(kept_mask[w2]);
    rank += __popcll(mykept & lmask_lt);
    int total = 0;
#pragma unroll
    for (int w2 = 0; w2 < 4; ++w2) total += __popcll(kept_mask[w2]);

    float* orow = out + (size_t)pair * TOPK * 5;
    if (alive && rank < TOPK) {
        float* o = orow + rank * 5;
        o[0] = v; o[1] = x1; o[2] = y1; o[3] = x2; o[4] = y2;
    }
    if (t < TOPK && t >= total) {
        float* o = orow + t * 5;
        o[0] = 0.f; o[1] = 0.f; o[2] = 0.f; o[3] = 0.f; o[4] = 0.f;
    }
}

extern "C" void kernel_launch(void* const* d_in, const int* in_sizes, int n_in,
                              void* d_out, int out_size, void* d_ws, size_t ws_size,
                              hipStream_t stream) {
    const float* loc = (const float*)d_in[0];
    const float* conf = (const float*)d_in[1];
    const float* prior = (const float*)d_in[2];
    float* out = (float*)d_out;
    float* probs = (float*)d_ws;            // [B][NFG][P] floats = 22.35 MB

    int P = in_sizes[2] / 4;                // 8732
    int B = in_sizes[0] / (4 * P);          // 32

    fused_postproc_kernel<<<dim3(B * NFG), dim3(KPRE), 0, stream>>>(
        conf, loc, prior, probs, out, B, P);
}

// Round 7
// 209.631 us; speedup vs baseline: 1.4266x; 1.4266x over previous
//
#include <hip/hip_runtime.h>
#include <stdint.h>

typedef unsigned long long ull;

#define NUM_CLASSES 21
#define NFG 20
#define TOPK 200
#define KPRE 256
#define CONF_TH 0.01f
#define NMS_TH 0.45f
#define VAR0 0.1f
#define VAR1 0.2f
#define NVMAX 35                 // ceil(8732/256)
#define F4_PER_CHUNK 1344        // 256 rows * 21 floats / 4
#define BITS_CONF 0x3C23D70Au    // __float_as_uint(0.01f)
#define BITS_ONE1 0x3F800001u    // just above 1.0f (softmax <= 1)
// skewed LDS slot: g, g+64, g+128, g+192 land in different banks
#define BSLOT(g) ((g) + ((g) >> 6))

// B..G shared state (verified pipeline). Union'd with the phase-A staging
// buffers — phase A finishes (with 2 syncthreads) before any of these is
// written.
struct NmsShared {
    ull arr[2 * KPRE];
    ull arr2[2 * KPRE];
    int wsum[2][4];
    int s_cnt;
    float4 sbox[KPRE + (KPRE >> 6)];
    float sarea[KPRE + (KPRE >> 6)];
    ull smask[KPRE][5];
    ull kept_mask[4];
};
union SmemU {
    float stage[2][256 * NUM_CLASSES];   // 2 x 21504 B double buffer
    NmsShared n;                          // ~23.7 KB
};

// Fully fused, ZERO inter-block communication. Round-6 lesson: a software
// grid barrier pays ~2560 device-scope L2 writeback/invalidate fences
// (~180 us) — worse than the dispatch boundary it replaced. Round-2 lesson:
// strided per-class conf gathers are L2-line-request-bound. This version:
// each (b,c) block reads image b's whole conf slab COALESCED (float4,
// 100% line utilization) through a double-buffered LDS stage and computes
// its own class's softmax scores locally (identical op order =>
// bit-identical to the verified two-kernel pipeline). 469 MB aggregate of
// coalesced L2 reads ~= 14 us of L2 bandwidth; XCD swizzle keeps each
// image slab (733 KB x 4 images = 2.9 MB) resident in its XCD's 4 MB L2.
__global__ __launch_bounds__(KPRE) void fused_postproc_kernel(
    const float* __restrict__ conf, const float* __restrict__ loc,
    const float* __restrict__ prior, float* __restrict__ out, int B, int P) {

    __shared__ __align__(16) SmemU smem;

    const int t = threadIdx.x;
    const int lane = t & 63;
    const int wid = t >> 6;
    const ull lmask_lt = (1ULL << lane) - 1ULL;

    // XCD-aware swizzle (bijective for B%8==0): all 20 class-blocks of an
    // image on one XCD -> conf slab read 20x from that XCD's L2, fetched
    // from HBM once.
    const int g = blockIdx.x;
    int b, c;
    if ((B & 7) == 0) {
        int k = g >> 3;
        b = ((k / NFG) << 3) + (g & 7);
        c = k - (k / NFG) * NFG;
    } else {
        b = g / NFG;
        c = g - (g / NFG) * NFG;
    }
    const int pair = b * NFG + c;

    // ---- Phase A: scores for class c of all P rows, via LDS-staged slab ----
    unsigned int ubits[NVMAX];
    {
        const int NCH = (P + 255) >> 8;                         // 35
        const float4* cs4 = (const float4*)(conf + (size_t)b * P * NUM_CLASSES);
        const int TOT4 = (P * NUM_CLASSES) >> 2;                // P%4==0

        // prologue: stage chunk 0
        {
            float4* d4 = (float4*)smem.stage[0];
#pragma unroll
            for (int u = 0; u < 6; ++u) {
                int i4 = (u << 8) + t;
                if (i4 < F4_PER_CHUNK && i4 < TOT4) d4[i4] = cs4[i4];
            }
        }
        __syncthreads();

        for (int k = 0; k < NCH; ++k) {
            const float* cur = smem.stage[k & 1];
            float* nxt = smem.stage[(k & 1) ^ 1];
            const bool have_next = (k + 1 < NCH);
            // issue next chunk's global loads early (latency hides under compute)
            float4 regs[6];
            if (have_next) {
                const int base4 = (k + 1) * F4_PER_CHUNK;
#pragma unroll
                for (int u = 0; u < 6; ++u) {
                    int i4 = (u << 8) + t;
                    regs[u] = (i4 < F4_PER_CHUNK && base4 + i4 < TOT4)
                                  ? cs4[base4 + i4]
                                  : make_float4(0.f, 0.f, 0.f, 0.f);
                }
            }
            // softmax score for row (k*256 + t), class c. Same op order as
            // the verified kernel: mx = fmax chain j=1..20 from x[0];
            // s = sum_{j=0..20} expf(x[j]-mx); score = expf(x[c+1]-mx)/s.
            // LDS row stride 21 (odd): lanes t,t+32 differ by 672 dwords
            // == 0 mod 32 banks -> 2-way aliasing (free).
            const int p = (k << 8) + t;
            if (p < P) {
                const float* row = cur + t * NUM_CLASSES;
                float mx = row[0];
#pragma unroll
                for (int j = 1; j < NUM_CLASSES; ++j) mx = fmaxf(mx, row[j]);
                float s = 0.f;
#pragma unroll
                for (int j = 0; j < NUM_CLASSES; ++j) s += expf(row[j] - mx);
                float e = expf(row[c + 1] - mx);
                ubits[k] = __float_as_uint(e / s);
            } else {
                ubits[k] = 0u;
            }
            __syncthreads();
            if (have_next) {
                float4* d4 = (float4*)nxt;
#pragma unroll
                for (int u = 0; u < 6; ++u) {
                    int i4 = (u << 8) + t;
                    if (i4 < F4_PER_CHUNK) d4[i4] = regs[u];
                }
            }
            __syncthreads();
        }
    }
    // From here on, smem.n is live (phase A fully synced out above).

    // B: WAVE-LOCAL binary search (no barriers, no shfl-reduce). Each wave
    // finds largest T_w with its own count >= 64 via ballot+popc (SALU).
    // Global T = min_w T_w  =>  count_global(>=T) >= 256 and T <= V256,
    // so {x >= T} is an exact superset of the global top-256.
    {
        unsigned int lo = BITS_CONF, hi = BITS_ONE1;
        while (hi - lo > 1u) {
            unsigned int mid = lo + ((hi - lo) >> 1);
            int cc = 0;
#pragma unroll
            for (int i = 0; i < NVMAX; ++i)
                cc += __popcll(__ballot(ubits[i] >= mid));
            if (cc >= KPRE / 4) lo = mid; else hi = mid;
        }
        if (lane == 0) smem.n.wsum[0][wid] = (int)lo;
    }
    __syncthreads();
    unsigned int T = (unsigned int)min(min(smem.n.wsum[0][0], smem.n.wsum[0][1]),
                                       min(smem.n.wsum[0][2], smem.n.wsum[0][3]));

    // C: ballot-compaction gather (cap 512) + exact-search fallback if the
    // wave-local threshold over-collects (>512: statistically never).
    int nval;
    for (int attempt = 0;; ++attempt) {
        if (t == 0) smem.n.s_cnt = 0;
        __syncthreads();
        int wtot = 0;
#pragma unroll
        for (int i = 0; i < NVMAX; ++i) {
            int p = (i << 8) + t;
            bool pred = (p < P) && (ubits[i] >= T);
            wtot += __popcll(__ballot(pred));
        }
        int wbase = 0;
        if (lane == 0) wbase = atomicAdd(&smem.n.s_cnt, wtot);
        wbase = __shfl(wbase, 0);
        int run = wbase;
#pragma unroll
        for (int i = 0; i < NVMAX; ++i) {
            int p = (i << 8) + t;
            bool pred = (p < P) && (ubits[i] >= T);
            ull bal = __ballot(pred);
            if (pred) {
                int slot = run + __popcll(bal & lmask_lt);
                if (slot < 2 * KPRE)
                    smem.n.arr[slot] = ((ull)ubits[i] << 32) | (unsigned int)(~p);
            }
            run += __popcll(bal);
        }
        __syncthreads();
        if (smem.n.s_cnt <= 2 * KPRE || attempt == 1) {
            nval = min(smem.n.s_cnt, 2 * KPRE);
            break;
        }
        // fallback: exact global search, lo invariant count>=256 holds at T
        unsigned int lo = T, hi = BITS_ONE1;
        int it = 0;
        while (hi - lo > 1u) {
            unsigned int mid = lo + ((hi - lo) >> 1);
            int cc = 0;
#pragma unroll
            for (int i = 0; i < NVMAX; ++i)
                cc += __popcll(__ballot(ubits[i] >= mid));
            if (lane == 0) smem.n.wsum[it & 1][wid] = cc;
            __syncthreads();
            int totc = smem.n.wsum[it & 1][0] + smem.n.wsum[it & 1][1] +
                       smem.n.wsum[it & 1][2] + smem.n.wsum[it & 1][3];
            if (totc >= KPRE) lo = mid; else hi = mid;
            ++it;
        }
        T = lo;
    }

    for (int e = t; e < 2 * KPRE; e += KPRE)
        if (e >= nval) smem.n.arr[e] = 0ULL;
    __syncthreads();

    // D: 512-wide bitonic sort, 2 keys/thread (elem t and t+256), descending.
    // key = (bits<<32)|~idx => value desc, index asc (JAX tie-break).
    // LDS stages double-buffered: one barrier per stage.
    ull k0 = smem.n.arr[t];
    ull k1 = smem.n.arr[t + KPRE];
    {
        int lstage = 0;
#pragma unroll
        for (int kk = 2; kk <= 2 * KPRE; kk <<= 1) {
#pragma unroll
            for (int j = kk >> 1; j > 0; j >>= 1) {
                if (j == KPRE) {
                    ull mx = (k0 > k1) ? k0 : k1;
                    ull mn = (k0 > k1) ? k1 : k0;
                    k0 = mx; k1 = mn;
                } else if (j >= 64) {
                    ull* A = (lstage & 1) ? smem.n.arr : smem.n.arr2;
                    ++lstage;
                    A[t] = k0; A[t + KPRE] = k1;
                    __syncthreads();
                    ull o0 = A[t ^ j];
                    ull o1 = A[(t + KPRE) ^ j];
                    bool amLow = ((t & j) == 0);
                    bool d0 = ((t & kk) == 0);
                    bool d1 = (((t + KPRE) & kk) == 0);
                    k0 = (d0 == amLow) ? ((k0 > o0) ? k0 : o0) : ((k0 > o0) ? o0 : k0);
                    k1 = (d1 == amLow) ? ((k1 > o1) ? k1 : o1) : ((k1 > o1) ? o1 : k1);
                } else {
                    ull o0 = __shfl_xor(k0, j);
                    ull o1 = __shfl_xor(k1, j);
                    bool amLow = ((t & j) == 0);
                    bool d0 = ((t & kk) == 0);
                    bool d1 = (((t + KPRE) & kk) == 0);
                    k0 = (d0 == amLow) ? ((k0 > o0) ? k0 : o0) : ((k0 > o0) ? o0 : k0);
                    k1 = (d1 == amLow) ? ((k1 > o1) ? k1 : o1) : ((k1 > o1) ? o1 : k1);
                }
            }
        }
    }
    const ull key = k0;    // top-256 sorted descending

    // E: decode candidate t
    float v = __uint_as_float((unsigned int)(key >> 32));
    int idx = (int)(~(unsigned int)(key & 0xFFFFFFFFu));
    if (idx < 0 || idx >= P) { idx = 0; v = 0.f; }

    const float4 lv = *(const float4*)(loc + ((size_t)b * P + idx) * 4);
    const float4 pv = *(const float4*)(prior + (size_t)idx * 4);
    float cx = pv.x + (lv.x * VAR0) * pv.z;
    float cy = pv.y + (lv.y * VAR0) * pv.w;
    float w = pv.z * expf(lv.z * VAR1);
    float h = pv.w * expf(lv.w * VAR1);
    float x1 = cx - w * 0.5f;
    float y1 = cy - h * 0.5f;
    float x2 = x1 + w;
    float y2 = y1 + h;
    float myarea = fmaxf(x2 - x1, 0.f) * fmaxf(y2 - y1, 0.f);

    smem.n.sbox[BSLOT(t)] = make_float4(x1, y1, x2, y2);
    smem.n.sarea[BSLOT(t)] = myarea;
    __syncthreads();

    // F1: balanced mask build (640 (row,tile) pairs over 256 threads)
#pragma unroll
    for (int rep = 0; rep < 3; ++rep) {
        int pid = t + (rep << 8);
        if (pid < 640) {
            int r, w2;
            if (pid < 64)       { r = pid;                w2 = 0; }
            else if (pid < 192) { int q = pid - 64;  r = 64  + (q >> 1); w2 = q & 1; }
            else if (pid < 384) { int q = pid - 192; int q3 = q / 3; r = 128 + q3; w2 = q - 3 * q3; }
            else                { int q = pid - 384; r = 192 + (q >> 2); w2 = q & 3; }
            float4 rb = smem.n.sbox[BSLOT(r)];
            float ra = smem.n.sarea[BSLOT(r)];
            ull mm = 0ULL;
            for (int i = 0; i < 64; ++i) {
                int gg = (w2 << 6) + i;
                float4 gb = smem.n.sbox[BSLOT(gg)];
                float lx = fmaxf(gb.x, rb.x), ly = fmaxf(gb.y, rb.y);
                float rx = fminf(gb.z, rb.z), ry = fminf(gb.w, rb.w);
                float iw = fmaxf(rx - lx, 0.f), ih = fmaxf(ry - ly, 0.f);
                float inter = iw * ih;
                float uni = smem.n.sarea[BSLOT(gg)] + ra - inter;
                bool s = (inter / fmaxf(uni, 1e-9f)) > NMS_TH;
                mm |= ((ull)(s ? 1u : 0u)) << i;
            }
            smem.n.smask[r][w2] = mm;
        }
    }
    __syncthreads();

    // F2: load row masks; resolve wave-serially, but only over lanes whose
    // suppression row is non-empty (todo) — suppressions are rare for random
    // boxes, so the 64-iter dependent-shfl chain shrinks to ~popc(todo).
    ull m0 = smem.n.smask[t][0];
    ull m1 = (wid >= 1) ? smem.n.smask[t][1] : 0ULL;
    ull m2 = (wid >= 2) ? smem.n.smask[t][2] : 0ULL;
    ull m3 = (wid >= 3) ? smem.n.smask[t][3] : 0ULL;
    if (wid == 0) m0 &= lmask_lt;
    else if (wid == 1) m1 &= lmask_lt;
    else if (wid == 2) m2 &= lmask_lt;
    else m3 &= lmask_lt;

    int alive = (v > CONF_TH) ? 1 : 0;
    ull mykept = 0ULL;
#pragma unroll
    for (int w2 = 0; w2 < 4; ++w2) {
        if (wid == w2) {
            if (w2 > 0 && (m0 & smem.n.kept_mask[0])) alive = 0;
            if (w2 > 1 && (m1 & smem.n.kept_mask[1])) alive = 0;
            if (w2 > 2 && (m2 & smem.n.kept_mask[2])) alive = 0;
            ull mw = (w2 == 0) ? m0 : (w2 == 1) ? m1 : (w2 == 2) ? m2 : m3;
            ull validb = __ballot(alive != 0);
            ull todo = __ballot((mw & validb) != 0ULL) & validb;
            ull kept = validb & ~todo;
            while (todo) {
                int i = __builtin_ctzll(todo);
                ull row = __shfl(mw, i);
                if ((row & kept) == 0ULL) kept |= (1ULL << i);
                todo &= (todo - 1ULL);
            }
            mykept = kept;
            alive = (int)((kept >> lane) & 1ULL);
            if (lane == 0) smem.n.kept_mask[w2] = kept;
        }
        __syncthreads();
    }

    // G: rank via popcounts, write kept rows + zero-fill
    int rank = 0;
#pragma unroll
    for (int w2 = 0; w2 < 4; ++w2)
        if (w2 < wid) rank += __popcll(smem.n.kept_mask[w2]);
    rank += __popcll(mykept & lmask_lt);
    int total = 0;
#pragma unroll
    for (int w2 = 0; w2 < 4; ++w2) total += __popcll(smem.n.kept_mask[w2]);

    float* orow = out + (size_t)pair * TOPK * 5;
    if (alive && rank < TOPK) {
        float* o = orow + rank * 5;
        o[0] = v; o[1] = x1; o[2] = y1; o[3] = x2; o[4] = y2;
    }
    if (t < TOPK && t >= total) {
        float* o = orow + t * 5;
        o[0] = 0.f; o[1] = 0.f; o[2] = 0.f; o[3] = 0.f; o[4] = 0.f;
    }
}

extern "C" void kernel_launch(void* const* d_in, const int* in_sizes, int n_in,
                              void* d_out, int out_size, void* d_ws, size_t ws_size,
                              hipStream_t stream) {
    const float* loc = (const float*)d_in[0];
    const float* conf = (const float*)d_in[1];
    const float* prior = (const float*)d_in[2];
    float* out = (float*)d_out;

    int P = in_sizes[2] / 4;                // 8732
    int B = in_sizes[0] / (4 * P);          // 32

    fused_postproc_kernel<<<dim3(B * NFG), dim3(KPRE), 0, stream>>>(
        conf, loc, prior, out, B, P);
}

// Round 8
// 139.942 us; speedup vs baseline: 2.1371x; 1.4980x over previous
//
#include <hip/hip_runtime.h>
#include <stdint.h>

typedef unsigned long long ull;
typedef float f4v __attribute__((ext_vector_type(4)));

#define NUM_CLASSES 21
#define NFG 20
#define TOPK 200
#define KPRE 256
#define CONF_TH 0.01f
#define NMS_TH 0.45f
#define VAR0 0.1f
#define VAR1 0.2f
#define NV4 9                    // ceil(8732/1024) float4-quads per thread
#define NVAL 36                  // NV4*4 score regs per thread
#define BITS_CONF 0x3C23D70Au    // __float_as_uint(0.01f)
#define BITS_ONE1 0x3F800001u    // just above 1.0f (softmax <= 1)
// skewed LDS slot: g, g+64, g+128, g+192 land in different banks
#define BSLOT(g) ((g) + ((g) >> 6))

// Kernel 1: softmax + transpose. Round-3 version was L1-request-bound: 21
// scalar stride-84B loads/row -> 1344 distinct-line requests per wave. This
// version: float4-vectorized staging (96 line-requests/wave), NONTEMPORAL
// conf loads (conf is dead after this read; don't evict the 22.35 MB probs
// we immediately re-read -- L2 is 32 MB, kernel1 touches 46 MB), and ONE
// 21.5 KB LDS buffer reused for the output transpose. Math op order is
// identical to the verified kernel => bit-identical probs.
__global__ __launch_bounds__(256) void softmax_probs_kernel(
    const float* __restrict__ conf, float* __restrict__ probs, int P) {
    __shared__ __align__(16) float buf[256 * NUM_CLASSES];   // 21504 B (reused)
    const int t = threadIdx.x;
    const int b = blockIdx.y;
    const int p0 = blockIdx.x << 8;
    const int cnt = min(256, P - p0);
    const float* src = conf + ((size_t)b * P + p0) * NUM_CLASSES;  // 16B aligned

    if (cnt == 256) {
        const f4v* s4 = (const f4v*)src;
        f4v* b4 = (f4v*)buf;
#pragma unroll
        for (int k = 0; k < 6; ++k) {
            int i = (k << 8) + t;
            if (i < (256 * NUM_CLASSES) / 4)
                b4[i] = __builtin_nontemporal_load(s4 + i);
        }
    } else {
        int n = cnt * NUM_CLASSES;
        for (int i = t; i < n; i += 256) buf[i] = src[i];
    }
    __syncthreads();

    float sc[NFG];
    if (t < cnt) {
        const float* row = buf + t * NUM_CLASSES;   // stride 21 => 2-way (free)
        float x[NUM_CLASSES];
        float mx = row[0];
        x[0] = mx;
#pragma unroll
        for (int j = 1; j < NUM_CLASSES; ++j) { x[j] = row[j]; mx = fmaxf(mx, x[j]); }
        float s = 0.f;
#pragma unroll
        for (int j = 0; j < NUM_CLASSES; ++j) { x[j] = expf(x[j] - mx); s += x[j]; }
#pragma unroll
        for (int c = 1; c < NUM_CLASSES; ++c)
            sc[c - 1] = x[c] / s;                   // true div: match ref ulps
    }
    __syncthreads();    // all row reads done before buf is overwritten

    if (t < cnt) {
#pragma unroll
        for (int c = 0; c < NFG; ++c)
            buf[c * 256 + t] = sc[c];               // transpose staging (5120 floats)
    }
    __syncthreads();

    float* dst = probs + ((size_t)b * NFG) * P + p0;
    if (cnt == 256) {
        // 20 classes x 64 float4; each wave stores one contiguous 1KB segment.
#pragma unroll
        for (int k = 0; k < 5; ++k) {
            int e = (k << 8) + t;
            int c = e >> 6;
            int f = e & 63;
            float4 val = ((const float4*)buf)[(c << 6) + f];
            *(float4*)(dst + (size_t)c * P + (f << 2)) = val;
        }
    } else {
        for (int e = t; e < NFG * cnt; e += 256) {
            int c = e / cnt;
            int f = e - c * cnt;
            dst[(size_t)c * P + f] = buf[c * 256 + f];
        }
    }
}

// Kernel 2: one block per (b, fg_class). Phase A reads the transposed probs
// row with float4 loads (9 VMEM insts vs 35 scalar). Element p for score reg
// i (i = j*4+e): p = (j<<10) + (t<<2) + e. Compaction order differs from the
// scalar version but the 512-wide total-order sort makes placement irrelevant.
// Requires P % 4 == 0 (P = 8732).
__global__ __launch_bounds__(KPRE) void nms_topk_kernel(
    const float* __restrict__ probs, const float* __restrict__ loc,
    const float* __restrict__ prior, float* __restrict__ out, int B, int P) {

    __shared__ ull arr[2 * KPRE];
    __shared__ ull arr2[2 * KPRE];              // double buffer for sort LDS stages
    __shared__ int wsum[2][4];
    __shared__ int s_cnt;
    __shared__ float4 sbox[KPRE + (KPRE >> 6)]; // skewed (BSLOT): no 4-way conflict
    __shared__ float sarea[KPRE + (KPRE >> 6)];
    __shared__ ull smask[KPRE][5];              // padded stride 40B: 2-way (free)
    __shared__ ull kept_mask[4];

    const int t = threadIdx.x;
    const int lane = t & 63;
    const int wid = t >> 6;
    const ull lmask_lt = (1ULL << lane) - 1ULL;

    // XCD-aware swizzle (bijective for B%8==0): all 20 classes of an image on
    // one XCD so probs/loc/prior reads reuse that XCD's L2.
    const int g = blockIdx.x;
    int b, c;
    if ((B & 7) == 0) {
        int k = g >> 3;
        b = ((k / NFG) << 3) + (g & 7);
        c = k - (k / NFG) * NFG;
    } else {
        b = g / NFG;
        c = g - (g / NFG) * NFG;
    }
    const int pair = b * NFG + c;
    const float* sp = probs + (size_t)pair * P;
    const int nq4 = P >> 2;                    // 2183

    // A: scores into registers via float4 (16B-aligned: pair*P*4 % 16 == 0)
    unsigned int ubits[NVAL];
    {
        const f4v* sp4 = (const f4v*)sp;
#pragma unroll
        for (int j = 0; j < NV4; ++j) {
            int q = (j << 8) + t;
            if (q < nq4) {
                f4v v = sp4[q];
#pragma unroll
                for (int e = 0; e < 4; ++e)
                    ubits[j * 4 + e] = __float_as_uint(v[e]);
            } else {
#pragma unroll
                for (int e = 0; e < 4; ++e) ubits[j * 4 + e] = 0u;
            }
        }
    }
    // p for reg i: ((i>>2)<<10) + (t<<2) + (i&3)
#define PIDX(i) ((((i) >> 2) << 10) + (t << 2) + ((i) & 3))

    // B: WAVE-LOCAL binary search (no barriers, no shfl-reduce). Each wave
    // finds largest T_w with its own count >= 64 via ballot+popc (SALU).
    // Global T = min_w T_w  =>  count_global(>=T) >= 256 and T <= V256,
    // so {x >= T} is an exact superset of the global top-256.
    {
        unsigned int lo = BITS_CONF, hi = BITS_ONE1;
        while (hi - lo > 1u) {
            unsigned int mid = lo + ((hi - lo) >> 1);
            int cc = 0;
#pragma unroll
            for (int i = 0; i < NVAL; ++i)
                cc += __popcll(__ballot(ubits[i] >= mid));
            if (cc >= KPRE / 4) lo = mid; else hi = mid;
        }
        if (lane == 0) wsum[0][wid] = (int)lo;
    }
    __syncthreads();
    unsigned int T = (unsigned int)min(min(wsum[0][0], wsum[0][1]),
                                       min(wsum[0][2], wsum[0][3]));

    // C: ballot-compaction gather (cap 512) + exact-search fallback if the
    // wave-local threshold over-collects (>512: statistically never).
    int nval;
    for (int attempt = 0;; ++attempt) {
        if (t == 0) s_cnt = 0;
        __syncthreads();
        int wtot = 0;
#pragma unroll
        for (int i = 0; i < NVAL; ++i) {
            int p = PIDX(i);
            bool pred = (p < P) && (ubits[i] >= T);
            wtot += __popcll(__ballot(pred));
        }
        int wbase = 0;
        if (lane == 0) wbase = atomicAdd(&s_cnt, wtot);
        wbase = __shfl(wbase, 0);
        int run = wbase;
#pragma unroll
        for (int i = 0; i < NVAL; ++i) {
            int p = PIDX(i);
            bool pred = (p < P) && (ubits[i] >= T);
            ull bal = __ballot(pred);
            if (pred) {
                int slot = run + __popcll(bal & lmask_lt);
                if (slot < 2 * KPRE)
                    arr[slot] = ((ull)ubits[i] << 32) | (unsigned int)(~p);
            }
            run += __popcll(bal);
        }
        __syncthreads();
        if (s_cnt <= 2 * KPRE || attempt == 1) { nval = min(s_cnt, 2 * KPRE); break; }
        // fallback: exact global search, lo invariant count>=256 holds at T
        unsigned int lo = T, hi = BITS_ONE1;
        int it = 0;
        while (hi - lo > 1u) {
            unsigned int mid = lo + ((hi - lo) >> 1);
            int cc = 0;
#pragma unroll
            for (int i = 0; i < NVAL; ++i)
                cc += __popcll(__ballot(ubits[i] >= mid));
            if (lane == 0) wsum[it & 1][wid] = cc;
            __syncthreads();
            int totc = wsum[it & 1][0] + wsum[it & 1][1] + wsum[it & 1][2] + wsum[it & 1][3];
            if (totc >= KPRE) lo = mid; else hi = mid;
            ++it;
        }
        T = lo;
    }

    for (int e = t; e < 2 * KPRE; e += KPRE)
        if (e >= nval) arr[e] = 0ULL;
    __syncthreads();

    // D: 512-wide bitonic sort, 2 keys/thread (elem t and t+256), descending.
    // key = (bits<<32)|~idx => value desc, index asc (JAX tie-break).
    // LDS stages double-buffered: one barrier per stage.
    ull k0 = arr[t];
    ull k1 = arr[t + KPRE];
    {
        int lstage = 0;
#pragma unroll
        for (int kk = 2; kk <= 2 * KPRE; kk <<= 1) {
#pragma unroll
            for (int j = kk >> 1; j > 0; j >>= 1) {
                if (j == KPRE) {
                    ull mx = (k0 > k1) ? k0 : k1;
                    ull mn = (k0 > k1) ? k1 : k0;
                    k0 = mx; k1 = mn;
                } else if (j >= 64) {
                    ull* A = (lstage & 1) ? arr : arr2;
                    ++lstage;
                    A[t] = k0; A[t + KPRE] = k1;
                    __syncthreads();
                    ull o0 = A[t ^ j];
                    ull o1 = A[(t + KPRE) ^ j];
                    bool amLow = ((t & j) == 0);
                    bool d0 = ((t & kk) == 0);
                    bool d1 = (((t + KPRE) & kk) == 0);
                    k0 = (d0 == amLow) ? ((k0 > o0) ? k0 : o0) : ((k0 > o0) ? o0 : k0);
                    k1 = (d1 == amLow) ? ((k1 > o1) ? k1 : o1) : ((k1 > o1) ? o1 : k1);
                } else {
                    ull o0 = __shfl_xor(k0, j);
                    ull o1 = __shfl_xor(k1, j);
                    bool amLow = ((t & j) == 0);
                    bool d0 = ((t & kk) == 0);
                    bool d1 = (((t + KPRE) & kk) == 0);
                    k0 = (d0 == amLow) ? ((k0 > o0) ? k0 : o0) : ((k0 > o0) ? o0 : k0);
                    k1 = (d1 == amLow) ? ((k1 > o1) ? k1 : o1) : ((k1 > o1) ? o1 : k1);
                }
            }
        }
    }
    const ull key = k0;    // top-256 sorted descending

    // E: decode candidate t
    float v = __uint_as_float((unsigned int)(key >> 32));
    int idx = (int)(~(unsigned int)(key & 0xFFFFFFFFu));
    if (idx < 0 || idx >= P) { idx = 0; v = 0.f; }

    const float4 lv = *(const float4*)(loc + ((size_t)b * P + idx) * 4);
    const float4 pv = *(const float4*)(prior + (size_t)idx * 4);
    float cx = pv.x + (lv.x * VAR0) * pv.z;
    float cy = pv.y + (lv.y * VAR0) * pv.w;
    float w = pv.z * expf(lv.z * VAR1);
    float h = pv.w * expf(lv.w * VAR1);
    float x1 = cx - w * 0.5f;
    float y1 = cy - h * 0.5f;
    float x2 = x1 + w;
    float y2 = y1 + h;
    float myarea = fmaxf(x2 - x1, 0.f) * fmaxf(y2 - y1, 0.f);

    sbox[BSLOT(t)] = make_float4(x1, y1, x2, y2);
    sarea[BSLOT(t)] = myarea;
    __syncthreads();

    // F1: balanced mask build (640 (row,tile) pairs over 256 threads)
#pragma unroll
    for (int rep = 0; rep < 3; ++rep) {
        int pid = t + (rep << 8);
        if (pid < 640) {
            int r, w2;
            if (pid < 64)       { r = pid;                w2 = 0; }
            else if (pid < 192) { int q = pid - 64;  r = 64  + (q >> 1); w2 = q & 1; }
            else if (pid < 384) { int q = pid - 192; int q3 = q / 3; r = 128 + q3; w2 = q - 3 * q3; }
            else                { int q = pid - 384; r = 192 + (q >> 2); w2 = q & 3; }
            float4 rb = sbox[BSLOT(r)];
            float ra = sarea[BSLOT(r)];
            ull mm = 0ULL;
            for (int i = 0; i < 64; ++i) {
                int gg = (w2 << 6) + i;
                float4 gb = sbox[BSLOT(gg)];
                float lx = fmaxf(gb.x, rb.x), ly = fmaxf(gb.y, rb.y);
                float rx = fminf(gb.z, rb.z), ry = fminf(gb.w, rb.w);
                float iw = fmaxf(rx - lx, 0.f), ih = fmaxf(ry - ly, 0.f);
                float inter = iw * ih;
                float uni = sarea[BSLOT(gg)] + ra - inter;
                bool s = (inter / fmaxf(uni, 1e-9f)) > NMS_TH;
                mm |= ((ull)(s ? 1u : 0u)) << i;
            }
            smask[r][w2] = mm;
        }
    }
    __syncthreads();

    // F2: load row masks; resolve wave-serially, but only over lanes whose
    // suppression row is non-empty (todo) — suppressions are rare for random
    // boxes, so the 64-iter dependent-shfl chain shrinks to ~popc(todo).
    ull m0 = smask[t][0];
    ull m1 = (wid >= 1) ? smask[t][1] : 0ULL;
    ull m2 = (wid >= 2) ? smask[t][2] : 0ULL;
    ull m3 = (wid >= 3) ? smask[t][3] : 0ULL;
    if (wid == 0) m0 &= lmask_lt;
    else if (wid == 1) m1 &= lmask_lt;
    else if (wid == 2) m2 &= lmask_lt;
    else m3 &= lmask_lt;

    int alive = (v > CONF_TH) ? 1 : 0;
    ull mykept = 0ULL;
#pragma unroll
    for (int w2 = 0; w2 < 4; ++w2) {
        if (wid == w2) {
            if (w2 > 0 && (m0 & kept_mask[0])) alive = 0;
            if (w2 > 1 && (m1 & kept_mask[1])) alive = 0;
            if (w2 > 2 && (m2 & kept_mask[2])) alive = 0;
            ull mw = (w2 == 0) ? m0 : (w2 == 1) ? m1 : (w2 == 2) ? m2 : m3;
            ull validb = __ballot(alive != 0);
            ull todo = __ballot((mw & validb) != 0ULL) & validb;
            ull kept = validb & ~todo;
            while (todo) {
                int i = __builtin_ctzll(todo);
                ull row = __shfl(mw, i);
                if ((row & kept) == 0ULL) kept |= (1ULL << i);
                todo &= (todo - 1ULL);
            }
            mykept = kept;
            alive = (int)((kept >> lane) & 1ULL);
            if (lane == 0) kept_mask[w2] = kept;
        }
        __syncthreads();
    }

    // G: rank via popcounts, write kept rows + zero-fill
    int rank = 0;
#pragma unroll
    for (int w2 = 0; w2 < 4; ++w2)
        if (w2 < wid) rank += __popcll(kept_mask[w2]);
    rank += __popcll(mykept & lmask_lt);
    int total = 0;
#pragma unroll
    for (int w2 = 0; w2 < 4; ++w2) total += __popcll(kept_mask[w2]);

    float* orow = out + (size_t)pair * TOPK * 5;
    if (alive && rank < TOPK) {
        float* o = orow + rank * 5;
        o[0] = v; o[1] = x1; o[2] = y1; o[3] = x2; o[4] = y2;
    }
    if (t < TOPK && t >= total) {
        float* o = orow + t * 5;
        o[0] = 0.f; o[1] = 0.f; o[2] = 0.f; o[3] = 0.f; o[4] = 0.f;
    }
#undef PIDX
}

extern "C" void kernel_launch(void* const* d_in, const int* in_sizes, int n_in,
                              void* d_out, int out_size, void* d_ws, size_t ws_size,
                              hipStream_t stream) {
    const float* loc = (const float*)d_in[0];
    const float* conf = (const float*)d_in[1];
    const float* prior = (const float*)d_in[2];
    float* out = (float*)d_out;
    float* probs = (float*)d_ws;            // [B][NFG][P] floats = 22.35 MB

    int P = in_sizes[2] / 4;                // 8732
    int B = in_sizes[0] / (4 * P);          // 32

    dim3 g1((P + 255) / 256, B);
    softmax_probs_kernel<<<g1, 256, 0, stream>>>(conf, probs, P);
    nms_topk_kernel<<<B * NFG, KPRE, 0, stream>>>(probs, loc, prior, out, B, P);
}

// Round 10
// 130.388 us; speedup vs baseline: 2.2937x; 1.0733x over previous
//
#include <hip/hip_runtime.h>
#include <stdint.h>

typedef unsigned long long ull;
typedef float f4v __attribute__((ext_vector_type(4)));

#define NUM_CLASSES 21
#define NFG 20
#define TOPK 200
#define KPRE 256
#define CONF_TH 0.01f
#define NMS_TH 0.45f
#define VAR0 0.1f
#define VAR1 0.2f
#define NVMAX 35                 // ceil(8732/256)
#define BITS_CONF 0x3C23D70Au    // __float_as_uint(0.01f)
// skewed LDS slot: g, g+64, g+128, g+192 land in different banks
#define BSLOT(g) ((g) + ((g) >> 6))

// Kernel 1: softmax + transpose. R0/R1/R3/R8 data: four different
// implementations all cost ~43 us (vs ~10 us instruction arithmetic), and the
// cost tracks the DIRTY-INTERMEDIATE size at the dispatch boundary (R2: 2.2 MB
// -> ~7 us). Theory: end-of-kernel dirty-L2 writeback walk at ~660 GB/s.
// This version streams probs with NONTEMPORAL stores so the boundary flush
// finds no dirty lines. Also: XCD swizzle matching the consumer (image b's
// probs produced and consumed on XCD b%8). Math op order identical to the
// verified kernel => bit-identical probs.
__global__ __launch_bounds__(256) void softmax_probs_kernel(
    const float* __restrict__ conf, float* __restrict__ probs, int B, int P) {
    __shared__ __align__(16) float buf[256 * NUM_CLASSES];   // 21504 B (reused)
    const int t = threadIdx.x;
    const int nch = (P + 255) >> 8;              // 35

    // XCD-align with nms: blocks with id%8 == r serve images with b%8 == r.
    const int id = blockIdx.x;
    int b, chk;
    if ((B & 7) == 0) {
        int r = id & 7, m = id >> 3;
        int q = m / nch;                          // image group 0..B/8-1
        b = r + (q << 3);
        chk = m - q * nch;
    } else {
        b = id / nch;
        chk = id - b * nch;
    }
    const int p0 = chk << 8;
    const int cnt = min(256, P - p0);
    const float* src = conf + ((size_t)b * P + p0) * NUM_CLASSES;  // 16B aligned

    if (cnt == 256) {
        const f4v* s4 = (const f4v*)src;
        f4v* b4 = (f4v*)buf;
#pragma unroll
        for (int k = 0; k < 6; ++k) {
            int i = (k << 8) + t;
            if (i < (256 * NUM_CLASSES) / 4)
                b4[i] = __builtin_nontemporal_load(s4 + i);
        }
    } else {
        int n = cnt * NUM_CLASSES;
        for (int i = t; i < n; i += 256) buf[i] = src[i];
    }
    __syncthreads();

    float sc[NFG];
    if (t < cnt) {
        const float* row = buf + t * NUM_CLASSES;   // stride 21 => 2-way (free)
        float x[NUM_CLASSES];
        float mx = row[0];
        x[0] = mx;
#pragma unroll
        for (int j = 1; j < NUM_CLASSES; ++j) { x[j] = row[j]; mx = fmaxf(mx, x[j]); }
        float s = 0.f;
#pragma unroll
        for (int j = 0; j < NUM_CLASSES; ++j) { x[j] = expf(x[j] - mx); s += x[j]; }
#pragma unroll
        for (int c = 1; c < NUM_CLASSES; ++c)
            sc[c - 1] = x[c] / s;                   // true div: match ref ulps
    }
    __syncthreads();    // all row reads done before buf is overwritten

    if (t < cnt) {
#pragma unroll
        for (int c = 0; c < NFG; ++c)
            buf[c * 256 + t] = sc[c];               // transpose staging
    }
    __syncthreads();

    float* dst = probs + ((size_t)b * NFG) * P + p0;
    if (cnt == 256) {
        // 20 classes x 64 float4; each wave stores one contiguous 1KB segment.
        // NT: leave nothing dirty in L2 for the boundary flush.
#pragma unroll
        for (int k = 0; k < 5; ++k) {
            int e = (k << 8) + t;
            int c = e >> 6;
            int f = e & 63;
            f4v val = ((const f4v*)buf)[(c << 6) + f];
            __builtin_nontemporal_store(val, (f4v*)(dst + (size_t)c * P + (f << 2)));
        }
    } else {
        for (int e = t; e < NFG * cnt; e += 256) {
            int c = e / cnt;
            int f = e - c * cnt;
            __builtin_nontemporal_store(buf[c * 256 + f], dst + (size_t)c * P + f);
        }
    }
}

// Kernel 2: one block per (b, fg_class). Phase A = R3 scalar coalesced loads
// (measured-best). Phase B = coarse 16-bit threshold search (10 iters vs 26:
// search the top-16 float bits; boundary-bin collisions add only a few
// candidates per wave and the >512 fallback covers the worst case exactly).
__global__ __launch_bounds__(KPRE) void nms_topk_kernel(
    const float* __restrict__ probs, const float* __restrict__ loc,
    const float* __restrict__ prior, float* __restrict__ out, int B, int P) {

    __shared__ ull arr[2 * KPRE];
    __shared__ ull arr2[2 * KPRE];              // double buffer for sort LDS stages
    __shared__ int wsum[2][4];
    __shared__ int s_cnt;
    __shared__ float4 sbox[KPRE + (KPRE >> 6)]; // skewed (BSLOT): no 4-way conflict
    __shared__ float sarea[KPRE + (KPRE >> 6)];
    __shared__ ull smask[KPRE][5];              // padded stride 40B: 2-way (free)
    __shared__ ull kept_mask[4];

    const int t = threadIdx.x;
    const int lane = t & 63;
    const int wid = t >> 6;
    const ull lmask_lt = (1ULL << lane) - 1ULL;

    // XCD-aware swizzle (bijective for B%8==0): all 20 classes of an image on
    // one XCD (b%8 == blockIdx%8, matching kernel1's producer placement).
    const int g = blockIdx.x;
    int b, c;
    if ((B & 7) == 0) {
        int k = g >> 3;
        b = ((k / NFG) << 3) + (g & 7);
        c = k - (k / NFG) * NFG;
    } else {
        b = g / NFG;
        c = g - (g / NFG) * NFG;
    }
    const int pair = b * NFG + c;
    const float* sp = probs + (size_t)pair * P;

    // A: scores into registers (coalesced dword loads)
    unsigned int ubits[NVMAX];
#pragma unroll
    for (int i = 0; i < NVMAX; ++i) {
        int p = (i << 8) + t;
        ubits[i] = (p < P) ? __float_as_uint(sp[p]) : 0u;
    }

    // B: WAVE-LOCAL coarse binary search on the TOP-16 float bits (10 iters).
    // Each wave finds largest T16 with count(bits >= T16<<16) >= 64 via
    // ballot+popc. Global T = min_w (T16_w<<16) => count_global(>=T) >= 256
    // and T <= V256, so {x >= T} remains an exact superset of the top-256.
    {
        unsigned int lo = 0x3C23u, hi = 0x3F81u;   // [~0.00995, >1.0] in top-16
        while (hi - lo > 1u) {
            unsigned int mid = lo + ((hi - lo) >> 1);
            unsigned int m32 = mid << 16;
            int cc = 0;
#pragma unroll
            for (int i = 0; i < NVMAX; ++i)
                cc += __popcll(__ballot(ubits[i] >= m32));
            if (cc >= KPRE / 4) lo = mid; else hi = mid;
        }
        if (lane == 0) wsum[0][wid] = (int)(lo << 16);
    }
    __syncthreads();
    unsigned int T = (unsigned int)min(min(wsum[0][0], wsum[0][1]),
                                       min(wsum[0][2], wsum[0][3]));

    // C: ballot-compaction gather (cap 512) + exact-search fallback if the
    // coarse threshold over-collects (>512: statistically never).
    int nval;
    for (int attempt = 0;; ++attempt) {
        if (t == 0) s_cnt = 0;
        __syncthreads();
        int wtot = 0;
#pragma unroll
        for (int i = 0; i < NVMAX; ++i) {
            int p = (i << 8) + t;
            bool pred = (p < P) && (ubits[i] >= T);
            wtot += __popcll(__ballot(pred));
        }
        int wbase = 0;
        if (lane == 0) wbase = atomicAdd(&s_cnt, wtot);
        wbase = __shfl(wbase, 0);
        int run = wbase;
#pragma unroll
        for (int i = 0; i < NVMAX; ++i) {
            int p = (i << 8) + t;
            bool pred = (p < P) && (ubits[i] >= T);
            ull bal = __ballot(pred);
            if (pred) {
                int slot = run + __popcll(bal & lmask_lt);
                if (slot < 2 * KPRE)
                    arr[slot] = ((ull)ubits[i] << 32) | (unsigned int)(~p);
            }
            run += __popcll(bal);
        }
        __syncthreads();
        if (s_cnt <= 2 * KPRE || attempt == 1) { nval = min(s_cnt, 2 * KPRE); break; }
        // fallback: exact 32-bit global search; count(>=T) > 512 >= 256 here
        unsigned int lo = T, hi = 0x3F800001u;
        int it = 0;
        while (hi - lo > 1u) {
            unsigned int mid = lo + ((hi - lo) >> 1);
            int cc = 0;
#pragma unroll
            for (int i = 0; i < NVMAX; ++i)
                cc += __popcll(__ballot(ubits[i] >= mid));
            if (lane == 0) wsum[it & 1][wid] = cc;
            __syncthreads();
            int totc = wsum[it & 1][0] + wsum[it & 1][1] + wsum[it & 1][2] + wsum[it & 1][3];
            if (totc >= KPRE) lo = mid; else hi = mid;
            ++it;
        }
        T = lo;
    }

    for (int e = t; e < 2 * KPRE; e += KPRE)
        if (e >= nval) arr[e] = 0ULL;
    __syncthreads();

    // D: 512-wide bitonic sort, 2 keys/thread (elem t and t+256), descending.
    // key = (bits<<32)|~idx => value desc, index asc (JAX tie-break).
    // LDS stages double-buffered: one barrier per stage.
    ull k0 = arr[t];
    ull k1 = arr[t + KPRE];
    {
        int lstage = 0;
#pragma unroll
        for (int kk = 2; kk <= 2 * KPRE; kk <<= 1) {
#pragma unroll
            for (int j = kk >> 1; j > 0; j >>= 1) {
                if (j == KPRE) {
                    ull mx = (k0 > k1) ? k0 : k1;
                    ull mn = (k0 > k1) ? k1 : k0;
                    k0 = mx; k1 = mn;
                } else if (j >= 64) {
                    ull* A = (lstage & 1) ? arr : arr2;
                    ++lstage;
                    A[t] = k0; A[t + KPRE] = k1;
                    __syncthreads();
                    ull o0 = A[t ^ j];
                    ull o1 = A[(t + KPRE) ^ j];
                    bool amLow = ((t & j) == 0);
                    bool d0 = ((t & kk) == 0);
                    bool d1 = (((t + KPRE) & kk) == 0);
                    k0 = (d0 == amLow) ? ((k0 > o0) ? k0 : o0) : ((k0 > o0) ? o0 : k0);
                    k1 = (d1 == amLow) ? ((k1 > o1) ? k1 : o1) : ((k1 > o1) ? o1 : k1);
                } else {
                    ull o0 = __shfl_xor(k0, j);
                    ull o1 = __shfl_xor(k1, j);
                    bool amLow = ((t & j) == 0);
                    bool d0 = ((t & kk) == 0);
                    bool d1 = (((t + KPRE) & kk) == 0);
                    k0 = (d0 == amLow) ? ((k0 > o0) ? k0 : o0) : ((k0 > o0) ? o0 : k0);
                    k1 = (d1 == amLow) ? ((k1 > o1) ? k1 : o1) : ((k1 > o1) ? o1 : k1);
                }
            }
        }
    }
    const ull key = k0;    // top-256 sorted descending

    // E: decode candidate t
    float v = __uint_as_float((unsigned int)(key >> 32));
    int idx = (int)(~(unsigned int)(key & 0xFFFFFFFFu));
    if (idx < 0 || idx >= P) { idx = 0; v = 0.f; }

    const float4 lv = *(const float4*)(loc + ((size_t)b * P + idx) * 4);
    const float4 pv = *(const float4*)(prior + (size_t)idx * 4);
    float cx = pv.x + (lv.x * VAR0) * pv.z;
    float cy = pv.y + (lv.y * VAR0) * pv.w;
    float w = pv.z * expf(lv.z * VAR1);
    float h = pv.w * expf(lv.w * VAR1);
    float x1 = cx - w * 0.5f;
    float y1 = cy - h * 0.5f;
    float x2 = x1 + w;
    float y2 = y1 + h;
    float myarea = fmaxf(x2 - x1, 0.f) * fmaxf(y2 - y1, 0.f);

    sbox[BSLOT(t)] = make_float4(x1, y1, x2, y2);
    sarea[BSLOT(t)] = myarea;
    __syncthreads();

    // F1: balanced mask build (640 (row,tile) pairs over 256 threads)
#pragma unroll
    for (int rep = 0; rep < 3; ++rep) {
        int pid = t + (rep << 8);
        if (pid < 640) {
            int r, w2;
            if (pid < 64)       { r = pid;                w2 = 0; }
            else if (pid < 192) { int q = pid - 64;  r = 64  + (q >> 1); w2 = q & 1; }
            else if (pid < 384) { int q = pid - 192; int q3 = q / 3; r = 128 + q3; w2 = q - 3 * q3; }
            else                { int q = pid - 384; r = 192 + (q >> 2); w2 = q & 3; }
            float4 rb = sbox[BSLOT(r)];
            float ra = sarea[BSLOT(r)];
            ull mm = 0ULL;
            for (int i = 0; i < 64; ++i) {
                int gg = (w2 << 6) + i;
                float4 gb = sbox[BSLOT(gg)];
                float lx = fmaxf(gb.x, rb.x), ly = fmaxf(gb.y, rb.y);
                float rx = fminf(gb.z, rb.z), ry = fminf(gb.w, rb.w);
                float iw = fmaxf(rx - lx, 0.f), ih = fmaxf(ry - ly, 0.f);
                float inter = iw * ih;
                float uni = sarea[BSLOT(gg)] + ra - inter;
                bool s = (inter / fmaxf(uni, 1e-9f)) > NMS_TH;
                mm |= ((ull)(s ? 1u : 0u)) << i;
            }
            smask[r][w2] = mm;
        }
    }
    __syncthreads();

    // F2: load row masks; resolve wave-serially, but only over lanes whose
    // suppression row is non-empty (todo) — suppressions are rare for random
    // boxes, so the 64-iter dependent-shfl chain shrinks to ~popc(todo).
    ull m0 = smask[t][0];
    ull m1 = (wid >= 1) ? smask[t][1] : 0ULL;
    ull m2 = (wid >= 2) ? smask[t][2] : 0ULL;
    ull m3 = (wid >= 3) ? smask[t][3] : 0ULL;
    if (wid == 0) m0 &= lmask_lt;
    else if (wid == 1) m1 &= lmask_lt;
    else if (wid == 2) m2 &= lmask_lt;
    else m3 &= lmask_lt;

    int alive = (v > CONF_TH) ? 1 : 0;
    ull mykept = 0ULL;
#pragma unroll
    for (int w2 = 0; w2 < 4; ++w2) {
        if (wid == w2) {
            if (w2 > 0 && (m0 & kept_mask[0])) alive = 0;
            if (w2 > 1 && (m1 & kept_mask[1])) alive = 0;
            if (w2 > 2 && (m2 & kept_mask[2])) alive = 0;
            ull mw = (w2 == 0) ? m0 : (w2 == 1) ? m1 : (w2 == 2) ? m2 : m3;
            ull validb = __ballot(alive != 0);
            ull todo = __ballot((mw & validb) != 0ULL) & validb;
            ull kept = validb & ~todo;
            while (todo) {
                int i = __builtin_ctzll(todo);
                ull row = __shfl(mw, i);
                if ((row & kept) == 0ULL) kept |= (1ULL << i);
                todo &= (todo - 1ULL);
            }
            mykept = kept;
            alive = (int)((kept >> lane) & 1ULL);
            if (lane == 0) kept_mask[w2] = kept;
        }
        __syncthreads();
    }

    // G: rank via popcounts, write kept rows + zero-fill
    int rank = 0;
#pragma unroll
    for (int w2 = 0; w2 < 4; ++w2)
        if (w2 < wid) rank += __popcll(kept_mask[w2]);
    rank += __popcll(mykept & lmask_lt);
    int total = 0;
#pragma unroll
    for (int w2 = 0; w2 < 4; ++w2) total += __popcll(kept_mask[w2]);

    float* orow = out + (size_t)pair * TOPK * 5;
    if (alive && rank < TOPK) {
        float* o = orow + rank * 5;
        o[0] = v; o[1] = x1; o[2] = y1; o[3] = x2; o[4] = y2;
    }
    if (t < TOPK && t >= total) {
        float* o = orow + t * 5;
        o[0] = 0.f; o[1] = 0.f; o[2] = 0.f; o[3] = 0.f; o[4] = 0.f;
    }
}

extern "C" void kernel_launch(void* const* d_in, const int* in_sizes, int n_in,
                              void* d_out, int out_size, void* d_ws, size_t ws_size,
                              hipStream_t stream) {
    const float* loc = (const float*)d_in[0];
    const float* conf = (const float*)d_in[1];
    const float* prior = (const float*)d_in[2];
    float* out = (float*)d_out;
    float* probs = (float*)d_ws;            // [B][NFG][P] floats = 22.35 MB

    int P = in_sizes[2] / 4;                // 8732
    int B = in_sizes[0] / (4 * P);          // 32
    int nch = (P + 255) / 256;              // 35

    softmax_probs_kernel<<<dim3(B * nch), 256, 0, stream>>>(conf, probs, B, P);
    nms_topk_kernel<<<B * NFG, KPRE, 0, stream>>>(probs, loc, prior, out, B, P);
}

// Round 12
// 126.778 us; speedup vs baseline: 2.3590x; 1.0285x over previous
//
#include <hip/hip_runtime.h>
#include <stdint.h>

typedef unsigned long long ull;
typedef float f4v __attribute__((ext_vector_type(4)));

#define NUM_CLASSES 21
#define NFG 20
#define TOPK 200
#define KPRE 256
#define CONF_TH 0.01f
#define NMS_TH 0.45f
#define VAR0 0.1f
#define VAR1 0.2f
#define NV16 18                  // ceil((8732/2)/256) uint regs (2 u16 scores each)
#define T16_LO 0x3C23u           // __float_as_uint(0.01f)>>16 (~0.00995 floor)
#define T16_HI 0x3F81u           // just above 1.0f in top-16 bits
// skewed LDS slot: g, g+64, g+128, g+192 land in different banks
#define BSLOT(g) ((g) + ((g) >> 6))

// Kernel 1: per-row softmax normalizers (mx, s) fp32 + TRUNCATED top-16-bit
// scores, transposed [B][NFG][P] u16. Intermediate = 2.2 + 11.2 = 13.4 MB
// (vs 22.35). Residual ledger: 2.2 MB -> ~42 us (R2), 22.35 MB -> ~77 us
// (R0/1/3/8/10, five kernel1 variants); this is the third point on that
// curve. Selection on u16 is EXACTLY the candidate set of R10's coarse
// search (u32 >= T16<<16 <=> u32>>16 >= T16); exact fp32 scores are
// re-derived in nms for candidates only, with identical op order =>
// bit-identical outputs. (R11 crash was a sign bug in the candidate gather
// guard, fixed in nms C2: sentinel index -1 passed `pa < P`.)
__global__ __launch_bounds__(256) void rownorm16_kernel(
    const float* __restrict__ conf, float2* __restrict__ norm,
    ushort* __restrict__ probs16, int B, int P) {
    __shared__ __align__(16) float buf[256 * NUM_CLASSES];   // 21504 B
    __shared__ __align__(16) ushort b16[NFG * 256];          // 10240 B transpose
    const int t = threadIdx.x;
    const int nch = (P + 255) >> 8;              // 35

    // XCD-align with nms consumers: id%8 == b%8.
    const int id = blockIdx.x;
    int b, chk;
    if ((B & 7) == 0) {
        int r = id & 7, m = id >> 3;
        int q = m / nch;
        b = r + (q << 3);
        chk = m - q * nch;
    } else {
        b = id / nch;
        chk = id - b * nch;
    }
    const int p0 = chk << 8;
    const int cnt = min(256, P - p0);
    const float* src = conf + ((size_t)b * P + p0) * NUM_CLASSES;  // 16B aligned

    if (cnt == 256) {
        const f4v* s4 = (const f4v*)src;
        f4v* b4 = (f4v*)buf;
#pragma unroll
        for (int k = 0; k < 6; ++k) {
            int i = (k << 8) + t;
            if (i < (256 * NUM_CLASSES) / 4) b4[i] = s4[i];   // plain: nms re-reads conf
        }
    } else {
        int n = cnt * NUM_CLASSES;
        for (int i = t; i < n; i += 256) buf[i] = src[i];
    }
    __syncthreads();

    if (t < cnt) {
        const float* row = buf + t * NUM_CLASSES;   // stride 21 => 2-way (free)
        float x[NUM_CLASSES];
        float mx = row[0];
        x[0] = mx;
#pragma unroll
        for (int j = 1; j < NUM_CLASSES; ++j) { x[j] = row[j]; mx = fmaxf(mx, x[j]); }
        float s = 0.f;
#pragma unroll
        for (int j = 0; j < NUM_CLASSES; ++j) { x[j] = expf(x[j] - mx); s += x[j]; }
        norm[(size_t)b * P + p0 + t] = make_float2(mx, s);    // coalesced 8B/lane
#pragma unroll
        for (int c = 1; c < NUM_CLASSES; ++c) {
            float v = x[c] / s;                     // true IEEE div (exact score)
            b16[(c - 1) * 256 + t] = (ushort)(__float_as_uint(v) >> 16);  // TRUNCATE
        }
    }
    __syncthreads();

    if (cnt == 256) {
        // 20 classes x 128 uints (2 u16 each); coalesced 512B/class segments.
        const uint* s32 = (const uint*)b16;
#pragma unroll
        for (int k = 0; k < 10; ++k) {
            int e = (k << 8) + t;
            int c = e >> 7;
            int q = e & 127;
            uint* dstu = (uint*)(probs16 + ((size_t)b * NFG + c) * P + p0);  // P,p0 even
            dstu[q] = s32[(c << 7) + q];
        }
    } else {
        for (int e = t; e < NFG * cnt; e += 256) {
            int c = e / cnt;
            int f = e - c * cnt;
            probs16[((size_t)b * NFG + c) * P + p0 + f] = b16[c * 256 + f];
        }
    }
}

// Kernel 2: one block per (b, fg_class). A: u16 scores coalesced (17.5 KB).
// B: wave-local coarse search on u16. C: compact candidate INDICES; then
// gather exact fp32 scores (expf(conf-mx)/s, bit-identical op order) for the
// <=512 candidates only. D..G unchanged verified pipeline.
__global__ __launch_bounds__(KPRE) void nms_topk_kernel(
    const float* __restrict__ conf, const float2* __restrict__ norm,
    const ushort* __restrict__ probs16, const float* __restrict__ loc,
    const float* __restrict__ prior, float* __restrict__ out, int B, int P) {

    __shared__ ull arr[2 * KPRE];
    __shared__ ull arr2[2 * KPRE];              // double buffer for sort LDS stages
    __shared__ int wsum[2][4];
    __shared__ int s_cnt;
    __shared__ float4 sbox[KPRE + (KPRE >> 6)]; // skewed (BSLOT): no 4-way conflict
    __shared__ float sarea[KPRE + (KPRE >> 6)];
    __shared__ ull smask[KPRE][5];              // padded stride 40B: 2-way (free)
    __shared__ ull kept_mask[4];

    const int t = threadIdx.x;
    const int lane = t & 63;
    const int wid = t >> 6;
    const ull lmask_lt = (1ULL << lane) - 1ULL;

    // XCD-aware swizzle (bijective for B%8==0): all 20 classes of an image on
    // one XCD (matching kernel1's producer placement).
    const int g = blockIdx.x;
    int b, c;
    if ((B & 7) == 0) {
        int k = g >> 3;
        b = ((k / NFG) << 3) + (g & 7);
        c = k - (k / NFG) * NFG;
    } else {
        b = g / NFG;
        c = g - (g / NFG) * NFG;
    }
    const int pair = b * NFG + c;
    const int nq = P >> 1;                      // 4366 uints (P even)

    // A: u16 scores into 18 uint regs (2 scores each), coalesced.
    unsigned int u2[NV16];
    {
        const uint* sp16 = (const uint*)(probs16 + (size_t)pair * P);  // 4B aligned
#pragma unroll
        for (int i = 0; i < NV16; ++i) {
            int q = (i << 8) + t;
            u2[i] = (q < nq) ? sp16[q] : 0u;    // 0 => never >= T16 (T16 >= 0x3C23)
        }
    }
    // score reg (i,h) corresponds to prior p = (((i<<8)+t)<<1)+h

    // B: WAVE-LOCAL coarse binary search on u16 (10 iters, no barriers).
    // Global T16 = min_w T16_w => global count >= 256 and T16<<16 <= V256 bits,
    // so {u16 >= T16} is an exact superset of the true top-256.
    {
        unsigned int lo = T16_LO, hi = T16_HI;
        while (hi - lo > 1u) {
            unsigned int mid = lo + ((hi - lo) >> 1);
            int cc = 0;
#pragma unroll
            for (int i = 0; i < NV16; ++i) {
                cc += __popcll(__ballot((u2[i] & 0xFFFFu) >= mid));
                cc += __popcll(__ballot((u2[i] >> 16) >= mid));
            }
            if (cc >= KPRE / 4) lo = mid; else hi = mid;
        }
        if (lane == 0) wsum[0][wid] = (int)lo;
    }
    __syncthreads();
    unsigned int T16 = (unsigned int)min(min(wsum[0][0], wsum[0][1]),
                                         min(wsum[0][2], wsum[0][3]));

    // C: ballot-compaction of candidate indices (cap 512) + block-wide exact
    // u16 search fallback if over-collected (>512: statistically never).
    int nval;
    for (int attempt = 0;; ++attempt) {
        if (t == 0) s_cnt = 0;
        __syncthreads();
        int wtot = 0;
#pragma unroll
        for (int i = 0; i < NV16; ++i) {
            wtot += __popcll(__ballot((u2[i] & 0xFFFFu) >= T16));
            wtot += __popcll(__ballot((u2[i] >> 16) >= T16));
        }
        int wbase = 0;
        if (lane == 0) wbase = atomicAdd(&s_cnt, wtot);
        wbase = __shfl(wbase, 0);
        int run = wbase;
#pragma unroll
        for (int i = 0; i < NV16; ++i) {
#pragma unroll
            for (int h = 0; h < 2; ++h) {
                unsigned int bits16 = h ? (u2[i] >> 16) : (u2[i] & 0xFFFFu);
                bool pred = (bits16 >= T16);
                ull bal = __ballot(pred);
                if (pred) {
                    int slot = run + __popcll(bal & lmask_lt);
                    if (slot < 2 * KPRE)
                        arr[slot] = (ull)(unsigned int)((((i << 8) + t) << 1) + h);
                }
                run += __popcll(bal);
            }
        }
        __syncthreads();
        if (s_cnt <= 2 * KPRE || attempt == 1) { nval = min(s_cnt, 2 * KPRE); break; }
        // fallback: block-wide exact u16 search for largest T16 with count>=256
        unsigned int lo = T16, hi = T16_HI;
        int it = 0;
        while (hi - lo > 1u) {
            unsigned int mid = lo + ((hi - lo) >> 1);
            int cc = 0;
#pragma unroll
            for (int i = 0; i < NV16; ++i) {
                cc += __popcll(__ballot((u2[i] & 0xFFFFu) >= mid));
                cc += __popcll(__ballot((u2[i] >> 16) >= mid));
            }
            if (lane == 0) wsum[it & 1][wid] = cc;
            __syncthreads();
            int totc = wsum[it & 1][0] + wsum[it & 1][1] + wsum[it & 1][2] + wsum[it & 1][3];
            if (totc >= KPRE) lo = mid; else hi = mid;
            ++it;
        }
        T16 = lo;
    }

    for (int e = t; e < 2 * KPRE; e += KPRE)
        if (e >= nval) arr[e] = (ull)0xFFFFFFFFu;   // sentinel index (invalid)
    __syncthreads();

    // C2: gather exact fp32 scores for my 2 candidate slots and build keys.
    // score = expf(conf[b,p,c+1] - mx_p)/s_p — identical inputs and op order
    // to kernel1's full score => bit-identical => sort/NMS/output unchanged.
    // UNSIGNED bounds guard: sentinel (-1 as int) must be invalid (R11 bug).
    const float* cb = conf + (size_t)b * P * NUM_CLASSES + (c + 1);
    const float2* nb = norm + (size_t)b * P;
    ull k0, k1;
    {
        unsigned int pa = (unsigned int)arr[t];
        unsigned int pb2 = (unsigned int)arr[t + KPRE];
        const bool va = (pa < (unsigned int)P);
        const bool vb = (pb2 < (unsigned int)P);
        float xa = 0.f, xb = 0.f;
        float2 ma = make_float2(0.f, 1.f), mb = make_float2(0.f, 1.f);
        if (va) { xa = cb[(size_t)pa * NUM_CLASSES]; ma = nb[pa]; }
        if (vb) { xb = cb[(size_t)pb2 * NUM_CLASSES]; mb = nb[pb2]; }
        if (va) {
            float v = expf(xa - ma.x) / ma.y;
            k0 = ((ull)__float_as_uint(v) << 32) | (unsigned int)(~pa);
        } else k0 = 0ULL;
        if (vb) {
            float v = expf(xb - mb.x) / mb.y;
            k1 = ((ull)__float_as_uint(v) << 32) | (unsigned int)(~pb2);
        } else k1 = 0ULL;
    }
    __syncthreads();

    // D: 512-wide bitonic sort, 2 keys/thread, descending.
    // key = (bits<<32)|~idx => value desc, index asc (JAX tie-break).
    {
        int lstage = 0;
#pragma unroll
        for (int kk = 2; kk <= 2 * KPRE; kk <<= 1) {
#pragma unroll
            for (int j = kk >> 1; j > 0; j >>= 1) {
                if (j == KPRE) {
                    ull mx = (k0 > k1) ? k0 : k1;
                    ull mn = (k0 > k1) ? k1 : k0;
                    k0 = mx; k1 = mn;
                } else if (j >= 64) {
                    ull* A = (lstage & 1) ? arr : arr2;
                    ++lstage;
                    A[t] = k0; A[t + KPRE] = k1;
                    __syncthreads();
                    ull o0 = A[t ^ j];
                    ull o1 = A[(t + KPRE) ^ j];
                    bool amLow = ((t & j) == 0);
                    bool d0 = ((t & kk) == 0);
                    bool d1 = (((t + KPRE) & kk) == 0);
                    k0 = (d0 == amLow) ? ((k0 > o0) ? k0 : o0) : ((k0 > o0) ? o0 : k0);
                    k1 = (d1 == amLow) ? ((k1 > o1) ? k1 : o1) : ((k1 > o1) ? o1 : k1);
                } else {
                    ull o0 = __shfl_xor(k0, j);
                    ull o1 = __shfl_xor(k1, j);
                    bool amLow = ((t & j) == 0);
                    bool d0 = ((t & kk) == 0);
                    bool d1 = (((t + KPRE) & kk) == 0);
                    k0 = (d0 == amLow) ? ((k0 > o0) ? k0 : o0) : ((k0 > o0) ? o0 : k0);
                    k1 = (d1 == amLow) ? ((k1 > o1) ? k1 : o1) : ((k1 > o1) ? o1 : k1);
                }
            }
        }
    }
    const ull key = k0;    // top-256 sorted descending

    // E: decode candidate t
    float v = __uint_as_float((unsigned int)(key >> 32));
    int idx = (int)(~(unsigned int)(key & 0xFFFFFFFFu));
    if (idx < 0 || idx >= P) { idx = 0; v = 0.f; }

    const float4 lv = *(const float4*)(loc + ((size_t)b * P + idx) * 4);
    const float4 pv = *(const float4*)(prior + (size_t)idx * 4);
    float cx = pv.x + (lv.x * VAR0) * pv.z;
    float cy = pv.y + (lv.y * VAR0) * pv.w;
    float w = pv.z * expf(lv.z * VAR1);
    float h = pv.w * expf(lv.w * VAR1);
    float x1 = cx - w * 0.5f;
    float y1 = cy - h * 0.5f;
    float x2 = x1 + w;
    float y2 = y1 + h;
    float myarea = fmaxf(x2 - x1, 0.f) * fmaxf(y2 - y1, 0.f);

    sbox[BSLOT(t)] = make_float4(x1, y1, x2, y2);
    sarea[BSLOT(t)] = myarea;
    __syncthreads();

    // F1: balanced mask build (640 (row,tile) pairs over 256 threads)
#pragma unroll
    for (int rep = 0; rep < 3; ++rep) {
        int pid = t + (rep << 8);
        if (pid < 640) {
            int r, w2;
            if (pid < 64)       { r = pid;                w2 = 0; }
            else if (pid < 192) { int q = pid - 64;  r = 64  + (q >> 1); w2 = q & 1; }
            else if (pid < 384) { int q = pid - 192; int q3 = q / 3; r = 128 + q3; w2 = q - 3 * q3; }
            else                { int q = pid - 384; r = 192 + (q >> 2); w2 = q & 3; }
            float4 rb = sbox[BSLOT(r)];
            float ra = sarea[BSLOT(r)];
            ull mm = 0ULL;
            for (int i = 0; i < 64; ++i) {
                int gg = (w2 << 6) + i;
                float4 gb = sbox[BSLOT(gg)];
                float lx = fmaxf(gb.x, rb.x), ly = fmaxf(gb.y, rb.y);
                float rx = fminf(gb.z, rb.z), ry = fminf(gb.w, rb.w);
                float iw = fmaxf(rx - lx, 0.f), ih = fmaxf(ry - ly, 0.f);
                float inter = iw * ih;
                float uni = sarea[BSLOT(gg)] + ra - inter;
                bool s = (inter / fmaxf(uni, 1e-9f)) > NMS_TH;
                mm |= ((ull)(s ? 1u : 0u)) << i;
            }
            smask[r][w2] = mm;
        }
    }
    __syncthreads();

    // F2: resolve wave-serially over non-empty rows only.
    ull m0 = smask[t][0];
    ull m1 = (wid >= 1) ? smask[t][1] : 0ULL;
    ull m2 = (wid >= 2) ? smask[t][2] : 0ULL;
    ull m3 = (wid >= 3) ? smask[t][3] : 0ULL;
    if (wid == 0) m0 &= lmask_lt;
    else if (wid == 1) m1 &= lmask_lt;
    else if (wid == 2) m2 &= lmask_lt;
    else m3 &= lmask_lt;

    int alive = (v > CONF_TH) ? 1 : 0;
    ull mykept = 0ULL;
#pragma unroll
    for (int w2 = 0; w2 < 4; ++w2) {
        if (wid == w2) {
            if (w2 > 0 && (m0 & kept_mask[0])) alive = 0;
            if (w2 > 1 && (m1 & kept_mask[1])) alive = 0;
            if (w2 > 2 && (m2 & kept_mask[2])) alive = 0;
            ull mw = (w2 == 0) ? m0 : (w2 == 1) ? m1 : (w2 == 2) ? m2 : m3;
            ull validb = __ballot(alive != 0);
            ull todo = __ballot((mw & validb) != 0ULL) & validb;
            ull kept = validb & ~todo;
            while (todo) {
                int i = __builtin_ctzll(todo);
                ull row = __shfl(mw, i);
                if ((row & kept) == 0ULL) kept |= (1ULL << i);
                todo &= (todo - 1ULL);
            }
            mykept = kept;
            alive = (int)((kept >> lane) & 1ULL);
            if (lane == 0) kept_mask[w2] = kept;
        }
        __syncthreads();
    }

    // G: rank via popcounts, write kept rows + zero-fill
    int rank = 0;
#pragma unroll
    for (int w2 = 0; w2 < 4; ++w2)
        if (w2 < wid) rank += __popcll(kept_mask[w2]);
    rank += __popcll(mykept & lmask_lt);
    int total = 0;
#pragma unroll
    for (int w2 = 0; w2 < 4; ++w2) total += __popcll(kept_mask[w2]);

    float* orow = out + (size_t)pair * TOPK * 5;
    if (alive && rank < TOPK) {
        float* o = orow + rank * 5;
        o[0] = v; o[1] = x1; o[2] = y1; o[3] = x2; o[4] = y2;
    }
    if (t < TOPK && t >= total) {
        float* o = orow + t * 5;
        o[0] = 0.f; o[1] = 0.f; o[2] = 0.f; o[3] = 0.f; o[4] = 0.f;
    }
}

extern "C" void kernel_launch(void* const* d_in, const int* in_sizes, int n_in,
                              void* d_out, int out_size, void* d_ws, size_t ws_size,
                              hipStream_t stream) {
    const float* loc = (const float*)d_in[0];
    const float* conf = (const float*)d_in[1];
    const float* prior = (const float*)d_in[2];
    float* out = (float*)d_out;

    int P = in_sizes[2] / 4;                // 8732
    int B = in_sizes[0] / (4 * P);          // 32
    int nch = (P + 255) / 256;              // 35

    float2* norm = (float2*)d_ws;                                   // 2.23 MB
    ushort* probs16 = (ushort*)((char*)d_ws + (size_t)B * P * 8);   // 11.17 MB (16B-aligned)

    rownorm16_kernel<<<dim3(B * nch), 256, 0, stream>>>(conf, norm, probs16, B, P);
    nms_topk_kernel<<<B * NFG, KPRE, 0, stream>>>(conf, norm, probs16, loc, prior, out, B, P);
}

// Round 13
// 122.958 us; speedup vs baseline: 2.4323x; 1.0311x over previous
//
#include <hip/hip_runtime.h>
#include <stdint.h>

typedef unsigned long long ull;
typedef float f4v __attribute__((ext_vector_type(4)));

#define NUM_CLASSES 21
#define NFG 20
#define TOPK 200
#define KPRE 256
#define NTHR 512                 // nms block size (8 waves)
#define CONF_TH 0.01f
#define NMS_TH 0.45f
#define VAR0 0.1f
#define VAR1 0.2f
#define NV9 9                    // ceil((8732/2)/512) uint regs (2 u16 scores each)
#define T16_LO 0x3C23u           // __float_as_uint(0.01f)>>16 (~0.00995 floor)
#define T16_HI 0x3F81u           // just above 1.0f in top-16 bits
// skewed LDS slot: g, g+64, g+128, g+192 land in different banks
#define BSLOT(g) ((g) + ((g) >> 6))

// Kernel 1: unchanged from R12 (verified). Per-row softmax normalizers (mx,s)
// fp32 + truncated top-16-bit scores, transposed [B][NFG][P] u16 (13.4 MB).
__global__ __launch_bounds__(256) void rownorm16_kernel(
    const float* __restrict__ conf, float2* __restrict__ norm,
    ushort* __restrict__ probs16, int B, int P) {
    __shared__ __align__(16) float buf[256 * NUM_CLASSES];   // 21504 B
    __shared__ __align__(16) ushort b16[NFG * 256];          // 10240 B transpose
    const int t = threadIdx.x;
    const int nch = (P + 255) >> 8;              // 35

    const int id = blockIdx.x;
    int b, chk;
    if ((B & 7) == 0) {
        int r = id & 7, m = id >> 3;
        int q = m / nch;
        b = r + (q << 3);
        chk = m - q * nch;
    } else {
        b = id / nch;
        chk = id - b * nch;
    }
    const int p0 = chk << 8;
    const int cnt = min(256, P - p0);
    const float* src = conf + ((size_t)b * P + p0) * NUM_CLASSES;  // 16B aligned

    if (cnt == 256) {
        const f4v* s4 = (const f4v*)src;
        f4v* b4 = (f4v*)buf;
#pragma unroll
        for (int k = 0; k < 6; ++k) {
            int i = (k << 8) + t;
            if (i < (256 * NUM_CLASSES) / 4) b4[i] = s4[i];
        }
    } else {
        int n = cnt * NUM_CLASSES;
        for (int i = t; i < n; i += 256) buf[i] = src[i];
    }
    __syncthreads();

    if (t < cnt) {
        const float* row = buf + t * NUM_CLASSES;   // stride 21 => 2-way (free)
        float x[NUM_CLASSES];
        float mx = row[0];
        x[0] = mx;
#pragma unroll
        for (int j = 1; j < NUM_CLASSES; ++j) { x[j] = row[j]; mx = fmaxf(mx, x[j]); }
        float s = 0.f;
#pragma unroll
        for (int j = 0; j < NUM_CLASSES; ++j) { x[j] = expf(x[j] - mx); s += x[j]; }
        norm[(size_t)b * P + p0 + t] = make_float2(mx, s);
#pragma unroll
        for (int c = 1; c < NUM_CLASSES; ++c) {
            float v = x[c] / s;                     // true IEEE div (exact score)
            b16[(c - 1) * 256 + t] = (ushort)(__float_as_uint(v) >> 16);
        }
    }
    __syncthreads();

    if (cnt == 256) {
        const uint* s32 = (const uint*)b16;
#pragma unroll
        for (int k = 0; k < 10; ++k) {
            int e = (k << 8) + t;
            int c = e >> 7;
            int q = e & 127;
            uint* dstu = (uint*)(probs16 + ((size_t)b * NFG + c) * P + p0);
            dstu[q] = s32[(c << 7) + q];
        }
    } else {
        for (int e = t; e < NFG * cnt; e += 256) {
            int c = e / cnt;
            int f = e - c * cnt;
            probs16[((size_t)b * NFG + c) * P + p0 + f] = b16[c * 256 + f];
        }
    }
}

// Kernel 2: one block per (b, fg_class), NOW 512 THREADS (8 waves).
// R12 profile: VALUBusy 52% @ Occupancy 21% — per-block serial VALU is the
// critical path. Halve per-thread work everywhere (A: 9 regs; B/C: 18 ballots
// per pass; D: 1 key/thread; F1: max 2 tiles) and double waves/CU for overlap.
// Selection lattice, candidate superset, exact-score gather, sort order all
// byte-identical to R12.
__global__ __launch_bounds__(NTHR) void nms_topk_kernel(
    const float* __restrict__ conf, const float2* __restrict__ norm,
    const ushort* __restrict__ probs16, const float* __restrict__ loc,
    const float* __restrict__ prior, float* __restrict__ out, int B, int P) {

    __shared__ ull arr[2 * KPRE];               // 512 sort keys
    __shared__ ull arr2[2 * KPRE];              // double buffer for sort LDS stages
    __shared__ int wsum[2][8];
    __shared__ int s_cnt;
    __shared__ float4 sbox[KPRE + (KPRE >> 6)]; // skewed (BSLOT): no 4-way conflict
    __shared__ float sarea[KPRE + (KPRE >> 6)];
    __shared__ ull smask[KPRE][5];              // padded stride 40B: 2-way (free)
    __shared__ ull kept_mask[4];

    const int t = threadIdx.x;
    const int lane = t & 63;
    const int wid = t >> 6;                     // 0..7
    const ull lmask_lt = (1ULL << lane) - 1ULL;

    // XCD-aware swizzle (bijective for B%8==0): all 20 classes of an image on
    // one XCD (matching kernel1's producer placement).
    const int g = blockIdx.x;
    int b, c;
    if ((B & 7) == 0) {
        int k = g >> 3;
        b = ((k / NFG) << 3) + (g & 7);
        c = k - (k / NFG) * NFG;
    } else {
        b = g / NFG;
        c = g - (g / NFG) * NFG;
    }
    const int pair = b * NFG + c;
    const int nq = P >> 1;                      // 4366 uints (P even)

    // A: u16 scores into 9 uint regs (2 scores each), coalesced.
    unsigned int u2[NV9];
    {
        const uint* sp16 = (const uint*)(probs16 + (size_t)pair * P);
#pragma unroll
        for (int i = 0; i < NV9; ++i) {
            int q = (i << 9) + t;
            u2[i] = (q < nq) ? sp16[q] : 0u;    // 0 => never >= T16
        }
    }
    // score reg (i,h) corresponds to prior p = (((i<<9)+t)<<1)+h

    // B: WAVE-LOCAL coarse binary search on u16 (10 iters, no barriers).
    // Per-wave target = KPRE/8 = 32; global T16 = min of 8 wave thresholds
    // => global count >= 256 and T16 <= V256's top-16 bits (same superset
    // proof as the 4-wave version).
    {
        unsigned int lo = T16_LO, hi = T16_HI;
        while (hi - lo > 1u) {
            unsigned int mid = lo + ((hi - lo) >> 1);
            int cc = 0;
#pragma unroll
            for (int i = 0; i < NV9; ++i) {
                cc += __popcll(__ballot((u2[i] & 0xFFFFu) >= mid));
                cc += __popcll(__ballot((u2[i] >> 16) >= mid));
            }
            if (cc >= KPRE / 8) lo = mid; else hi = mid;
        }
        if (lane == 0) wsum[0][wid] = (int)lo;
    }
    __syncthreads();
    unsigned int T16;
    {
        int m = wsum[0][0];
#pragma unroll
        for (int w = 1; w < 8; ++w) m = min(m, wsum[0][w]);
        T16 = (unsigned int)m;
    }

    // C: ballot-compaction of candidate indices (cap 512) + block-wide exact
    // u16 search fallback if over-collected (>512: statistically never).
    int nval;
    for (int attempt = 0;; ++attempt) {
        if (t == 0) s_cnt = 0;
        __syncthreads();
        int wtot = 0;
#pragma unroll
        for (int i = 0; i < NV9; ++i) {
            wtot += __popcll(__ballot((u2[i] & 0xFFFFu) >= T16));
            wtot += __popcll(__ballot((u2[i] >> 16) >= T16));
        }
        int wbase = 0;
        if (lane == 0) wbase = atomicAdd(&s_cnt, wtot);
        wbase = __shfl(wbase, 0);
        int run = wbase;
#pragma unroll
        for (int i = 0; i < NV9; ++i) {
#pragma unroll
            for (int h = 0; h < 2; ++h) {
                unsigned int bits16 = h ? (u2[i] >> 16) : (u2[i] & 0xFFFFu);
                bool pred = (bits16 >= T16);
                ull bal = __ballot(pred);
                if (pred) {
                    int slot = run + __popcll(bal & lmask_lt);
                    if (slot < 2 * KPRE)
                        arr[slot] = (ull)(unsigned int)((((i << 9) + t) << 1) + h);
                }
                run += __popcll(bal);
            }
        }
        __syncthreads();
        if (s_cnt <= 2 * KPRE || attempt == 1) { nval = min(s_cnt, 2 * KPRE); break; }
        // fallback: block-wide exact u16 search for largest T16 with count>=256
        unsigned int lo = T16, hi = T16_HI;
        int it = 0;
        while (hi - lo > 1u) {
            unsigned int mid = lo + ((hi - lo) >> 1);
            int cc = 0;
#pragma unroll
            for (int i = 0; i < NV9; ++i) {
                cc += __popcll(__ballot((u2[i] & 0xFFFFu) >= mid));
                cc += __popcll(__ballot((u2[i] >> 16) >= mid));
            }
            if (lane == 0) wsum[it & 1][wid] = cc;
            __syncthreads();
            int totc = 0;
#pragma unroll
            for (int w = 0; w < 8; ++w) totc += wsum[it & 1][w];
            if (totc >= KPRE) lo = mid; else hi = mid;
            ++it;
        }
        T16 = lo;
    }

    if (t >= nval) arr[t] = (ull)0xFFFFFFFFu;   // sentinel index (invalid)
    __syncthreads();

    // C2: gather exact fp32 score for MY candidate slot (1/thread).
    // score = expf(conf[b,p,c+1] - mx_p)/s_p — identical inputs and op order
    // to kernel1's full score => bit-identical => sort/NMS/output unchanged.
    // UNSIGNED bounds guard (R11 lesson: sentinel -1 must be invalid).
    const float* cb = conf + (size_t)b * P * NUM_CLASSES + (c + 1);
    const float2* nb = norm + (size_t)b * P;
    ull k0;
    {
        unsigned int pa = (unsigned int)arr[t];
        if (pa < (unsigned int)P) {
            float xa = cb[(size_t)pa * NUM_CLASSES];
            float2 ma = nb[pa];
            float v = expf(xa - ma.x) / ma.y;
            k0 = ((ull)__float_as_uint(v) << 32) | (unsigned int)(~pa);
        } else {
            k0 = 0ULL;
        }
    }
    __syncthreads();

    // D: 512-wide bitonic sort, ONE key/thread, descending.
    // key = (bits<<32)|~idx => value desc, index asc (JAX tie-break).
    // j>=64 via double-buffered LDS (6 stages); j<64 via shfl_xor.
    {
        int lstage = 0;
#pragma unroll
        for (int kk = 2; kk <= 2 * KPRE; kk <<= 1) {
#pragma unroll
            for (int j = kk >> 1; j > 0; j >>= 1) {
                bool amLow = ((t & j) == 0);
                bool d0 = ((t & kk) == 0);
                if (j >= 64) {
                    ull* A = (lstage & 1) ? arr : arr2;
                    ++lstage;
                    A[t] = k0;
                    __syncthreads();
                    ull o0 = A[t ^ j];
                    k0 = (d0 == amLow) ? ((k0 > o0) ? k0 : o0) : ((k0 > o0) ? o0 : k0);
                } else {
                    ull o0 = __shfl_xor(k0, j);
                    k0 = (d0 == amLow) ? ((k0 > o0) ? k0 : o0) : ((k0 > o0) ? o0 : k0);
                }
            }
        }
    }
    const ull key = k0;    // threads 0..255 hold the top-256, sorted descending

    // E: decode candidate t (threads < 256 only)
    float v = 0.f, x1 = 0.f, y1 = 0.f, x2 = 0.f, y2 = 0.f;
    if (t < KPRE) {
        v = __uint_as_float((unsigned int)(key >> 32));
        int idx = (int)(~(unsigned int)(key & 0xFFFFFFFFu));
        if (idx < 0 || idx >= P) { idx = 0; v = 0.f; }

        const float4 lv = *(const float4*)(loc + ((size_t)b * P + idx) * 4);
        const float4 pv = *(const float4*)(prior + (size_t)idx * 4);
        float cx = pv.x + (lv.x * VAR0) * pv.z;
        float cy = pv.y + (lv.y * VAR0) * pv.w;
        float w = pv.z * expf(lv.z * VAR1);
        float h = pv.w * expf(lv.w * VAR1);
        x1 = cx - w * 0.5f;
        y1 = cy - h * 0.5f;
        x2 = x1 + w;
        y2 = y1 + h;
        float myarea = fmaxf(x2 - x1, 0.f) * fmaxf(y2 - y1, 0.f);
        sbox[BSLOT(t)] = make_float4(x1, y1, x2, y2);
        sarea[BSLOT(t)] = myarea;
    }
    __syncthreads();

    // F1: balanced mask build (640 (row,tile) pairs over 512 threads, max 2)
#pragma unroll
    for (int rep = 0; rep < 2; ++rep) {
        int pid = t + (rep << 9);
        if (pid < 640) {
            int r, w2;
            if (pid < 64)       { r = pid;                w2 = 0; }
            else if (pid < 192) { int q = pid - 64;  r = 64  + (q >> 1); w2 = q & 1; }
            else if (pid < 384) { int q = pid - 192; int q3 = q / 3; r = 128 + q3; w2 = q - 3 * q3; }
            else                { int q = pid - 384; r = 192 + (q >> 2); w2 = q & 3; }
            float4 rb = sbox[BSLOT(r)];
            float ra = sarea[BSLOT(r)];
            ull mm = 0ULL;
            for (int i = 0; i < 64; ++i) {
                int gg = (w2 << 6) + i;
                float4 gb = sbox[BSLOT(gg)];
                float lx = fmaxf(gb.x, rb.x), ly = fmaxf(gb.y, rb.y);
                float rx = fminf(gb.z, rb.z), ry = fminf(gb.w, rb.w);
                float iw = fmaxf(rx - lx, 0.f), ih = fmaxf(ry - ly, 0.f);
                float inter = iw * ih;
                float uni = sarea[BSLOT(gg)] + ra - inter;
                bool s = (inter / fmaxf(uni, 1e-9f)) > NMS_TH;
                mm |= ((ull)(s ? 1u : 0u)) << i;
            }
            smask[r][w2] = mm;
        }
    }
    __syncthreads();

    // F2: waves 0..3 resolve (t < 256); waves 4..7 just pass the barriers.
    ull m0 = 0ULL, m1 = 0ULL, m2 = 0ULL, m3 = 0ULL;
    if (t < KPRE) {
        m0 = smask[t][0];
        m1 = (wid >= 1) ? smask[t][1] : 0ULL;
        m2 = (wid >= 2) ? smask[t][2] : 0ULL;
        m3 = (wid >= 3) ? smask[t][3] : 0ULL;
        if (wid == 0) m0 &= lmask_lt;
        else if (wid == 1) m1 &= lmask_lt;
        else if (wid == 2) m2 &= lmask_lt;
        else m3 &= lmask_lt;
    }

    int alive = (t < KPRE && v > CONF_TH) ? 1 : 0;
    ull mykept = 0ULL;
#pragma unroll
    for (int w2 = 0; w2 < 4; ++w2) {
        if (wid == w2) {          // only true for t < 256
            if (w2 > 0 && (m0 & kept_mask[0])) alive = 0;
            if (w2 > 1 && (m1 & kept_mask[1])) alive = 0;
            if (w2 > 2 && (m2 & kept_mask[2])) alive = 0;
            ull mw = (w2 == 0) ? m0 : (w2 == 1) ? m1 : (w2 == 2) ? m2 : m3;
            ull validb = __ballot(alive != 0);
            ull todo = __ballot((mw & validb) != 0ULL) & validb;
            ull kept = validb & ~todo;
            while (todo) {
                int i = __builtin_ctzll(todo);
                ull row = __shfl(mw, i);
                if ((row & kept) == 0ULL) kept |= (1ULL << i);
                todo &= (todo - 1ULL);
            }
            mykept = kept;
            alive = (int)((kept >> lane) & 1ULL);
            if (lane == 0) kept_mask[w2] = kept;
        }
        __syncthreads();
    }

    // G: rank via popcounts, write kept rows + zero-fill (t < 256 relevant)
    int rank = 0;
#pragma unroll
    for (int w2 = 0; w2 < 4; ++w2)
        if (w2 < wid) rank += __popcll(kept_mask[w2]);
    rank += __popcll(mykept & lmask_lt);
    int total = 0;
#pragma unroll
    for (int w2 = 0; w2 < 4; ++w2) total += __popcll(kept_mask[w2]);

    float* orow = out + (size_t)pair * TOPK * 5;
    if (alive && rank < TOPK) {
        float* o = orow + rank * 5;
        o[0] = v; o[1] = x1; o[2] = y1; o[3] = x2; o[4] = y2;
    }
    if (t < TOPK && t >= total) {
        float* o = orow + t * 5;
        o[0] = 0.f; o[1] = 0.f; o[2] = 0.f; o[3] = 0.f; o[4] = 0.f;
    }
}

extern "C" void kernel_launch(void* const* d_in, const int* in_sizes, int n_in,
                              void* d_out, int out_size, void* d_ws, size_t ws_size,
                              hipStream_t stream) {
    const float* loc = (const float*)d_in[0];
    const float* conf = (const float*)d_in[1];
    const float* prior = (const float*)d_in[2];
    float* out = (float*)d_out;

    int P = in_sizes[2] / 4;                // 8732
    int B = in_sizes[0] / (4 * P);          // 32
    int nch = (P + 255) / 256;              // 35

    float2* norm = (float2*)d_ws;                                   // 2.23 MB
    ushort* probs16 = (ushort*)((char*)d_ws + (size_t)B * P * 8);   // 11.17 MB (16B-aligned)

    rownorm16_kernel<<<dim3(B * nch), 256, 0, stream>>>(conf, norm, probs16, B, P);
    nms_topk_kernel<<<B * NFG, NTHR, 0, stream>>>(conf, norm, probs16, loc, prior, out, B, P);
}

// Round 14
// 122.117 us; speedup vs baseline: 2.4490x; 1.0069x over previous
//
#include <hip/hip_runtime.h>
#include <stdint.h>

typedef unsigned long long ull;
typedef float f4v __attribute__((ext_vector_type(4)));

#define NUM_CLASSES 21
#define NFG 20
#define TOPK 200
#define KPRE 256
#define NTHR 512                 // nms block size (8 waves)
#define CONF_TH 0.01f
#define NMS_TH 0.45f
#define VAR0 0.1f
#define VAR1 0.2f
#define NV9 9                    // ceil((8732/2)/512) uint regs (2 u16 scores each)
#define T16_LO 0x3C23u           // __float_as_uint(0.01f)>>16 (~0.00995 floor)
#define T16_HI 0x3F81u           // just above 1.0f in top-16 bits
// skewed LDS slot: g, g+64, g+128, g+192 land in different banks
#define BSLOT(g) ((g) + ((g) >> 6))

// Kernel 1: per-row softmax normalizers + truncated u16 scores (13.4 MB).
// SINGLE CHANGE vs R13: all intermediate stores are AGENT-SCOPE
// (__hip_atomic_store => global_store with write-through sc bits). R10 showed
// plain nontemporal stores don't help (nt = replacement hint, lines stay
// dirty); agent-scope stores land at the device coherence point and leave the
// per-XCD L2 CLEAN, so the pre-nms dependency drain has nothing to walk.
// This tests the last store flavor against the ~40 us kernel1-side anomaly
// (13.4 MB coalesced stores at an effective 350 GB/s is 20x below HW).
__global__ __launch_bounds__(256) void rownorm16_kernel(
    const float* __restrict__ conf, float2* __restrict__ norm,
    ushort* __restrict__ probs16, int B, int P) {
    __shared__ __align__(16) float buf[256 * NUM_CLASSES];   // 21504 B
    __shared__ __align__(16) ushort b16[NFG * 256];          // 10240 B transpose
    const int t = threadIdx.x;
    const int nch = (P + 255) >> 8;              // 35

    const int id = blockIdx.x;
    int b, chk;
    if ((B & 7) == 0) {
        int r = id & 7, m = id >> 3;
        int q = m / nch;
        b = r + (q << 3);
        chk = m - q * nch;
    } else {
        b = id / nch;
        chk = id - b * nch;
    }
    const int p0 = chk << 8;
    const int cnt = min(256, P - p0);
    const float* src = conf + ((size_t)b * P + p0) * NUM_CLASSES;  // 16B aligned

    if (cnt == 256) {
        const f4v* s4 = (const f4v*)src;
        f4v* b4 = (f4v*)buf;
#pragma unroll
        for (int k = 0; k < 6; ++k) {
            int i = (k << 8) + t;
            if (i < (256 * NUM_CLASSES) / 4) b4[i] = s4[i];
        }
    } else {
        int n = cnt * NUM_CLASSES;
        for (int i = t; i < n; i += 256) buf[i] = src[i];
    }
    __syncthreads();

    if (t < cnt) {
        const float* row = buf + t * NUM_CLASSES;   // stride 21 => 2-way (free)
        float x[NUM_CLASSES];
        float mx = row[0];
        x[0] = mx;
#pragma unroll
        for (int j = 1; j < NUM_CLASSES; ++j) { x[j] = row[j]; mx = fmaxf(mx, x[j]); }
        float s = 0.f;
#pragma unroll
        for (int j = 0; j < NUM_CLASSES; ++j) { x[j] = expf(x[j] - mx); s += x[j]; }
        // agent-scope 8B store of (mx, s)
        ull nv = (ull)__float_as_uint(mx) | ((ull)__float_as_uint(s) << 32);
        __hip_atomic_store((ull*)(norm + (size_t)b * P + p0 + t), nv,
                           __ATOMIC_RELAXED, __HIP_MEMORY_SCOPE_AGENT);
#pragma unroll
        for (int c = 1; c < NUM_CLASSES; ++c) {
            float v = x[c] / s;                     // true IEEE div (exact score)
            b16[(c - 1) * 256 + t] = (ushort)(__float_as_uint(v) >> 16);
        }
    }
    __syncthreads();

    if (cnt == 256) {
        // 20 classes x 128 uints; agent-scope dword stores (still coalesced).
        const uint* s32 = (const uint*)b16;
#pragma unroll
        for (int k = 0; k < 10; ++k) {
            int e = (k << 8) + t;
            int c = e >> 7;
            int q = e & 127;
            uint* dstu = (uint*)(probs16 + ((size_t)b * NFG + c) * P + p0);
            __hip_atomic_store(dstu + q, s32[(c << 7) + q],
                               __ATOMIC_RELAXED, __HIP_MEMORY_SCOPE_AGENT);
        }
    } else {
        for (int e = t; e < NFG * cnt; e += 256) {
            int c = e / cnt;
            int f = e - c * cnt;
            __hip_atomic_store(probs16 + ((size_t)b * NFG + c) * P + p0 + f,
                               b16[c * 256 + f],
                               __ATOMIC_RELAXED, __HIP_MEMORY_SCOPE_AGENT);
        }
    }
}

// Kernel 2: unchanged from R13 (verified). One block per (b, fg_class),
// 512 threads. A: u16 coalesced. B: wave-local coarse search. C: index
// compaction + exact fp32 re-derivation for <=512 candidates. D: 512-wide
// 1-key/thread bitonic sort. E..G: verified NMS pipeline.
__global__ __launch_bounds__(NTHR) void nms_topk_kernel(
    const float* __restrict__ conf, const float2* __restrict__ norm,
    const ushort* __restrict__ probs16, const float* __restrict__ loc,
    const float* __restrict__ prior, float* __restrict__ out, int B, int P) {

    __shared__ ull arr[2 * KPRE];               // 512 sort keys
    __shared__ ull arr2[2 * KPRE];              // double buffer for sort LDS stages
    __shared__ int wsum[2][8];
    __shared__ int s_cnt;
    __shared__ float4 sbox[KPRE + (KPRE >> 6)]; // skewed (BSLOT): no 4-way conflict
    __shared__ float sarea[KPRE + (KPRE >> 6)];
    __shared__ ull smask[KPRE][5];              // padded stride 40B: 2-way (free)
    __shared__ ull kept_mask[4];

    const int t = threadIdx.x;
    const int lane = t & 63;
    const int wid = t >> 6;                     // 0..7
    const ull lmask_lt = (1ULL << lane) - 1ULL;

    const int g = blockIdx.x;
    int b, c;
    if ((B & 7) == 0) {
        int k = g >> 3;
        b = ((k / NFG) << 3) + (g & 7);
        c = k - (k / NFG) * NFG;
    } else {
        b = g / NFG;
        c = g - (g / NFG) * NFG;
    }
    const int pair = b * NFG + c;
    const int nq = P >> 1;                      // 4366 uints (P even)

    // A: u16 scores into 9 uint regs (2 scores each), coalesced.
    unsigned int u2[NV9];
    {
        const uint* sp16 = (const uint*)(probs16 + (size_t)pair * P);
#pragma unroll
        for (int i = 0; i < NV9; ++i) {
            int q = (i << 9) + t;
            u2[i] = (q < nq) ? sp16[q] : 0u;    // 0 => never >= T16
        }
    }
    // score reg (i,h) corresponds to prior p = (((i<<9)+t)<<1)+h

    // B: WAVE-LOCAL coarse binary search on u16 (10 iters, no barriers).
    // Per-wave target = KPRE/8 = 32; global T16 = min of 8 wave thresholds.
    {
        unsigned int lo = T16_LO, hi = T16_HI;
        while (hi - lo > 1u) {
            unsigned int mid = lo + ((hi - lo) >> 1);
            int cc = 0;
#pragma unroll
            for (int i = 0; i < NV9; ++i) {
                cc += __popcll(__ballot((u2[i] & 0xFFFFu) >= mid));
                cc += __popcll(__ballot((u2[i] >> 16) >= mid));
            }
            if (cc >= KPRE / 8) lo = mid; else hi = mid;
        }
        if (lane == 0) wsum[0][wid] = (int)lo;
    }
    __syncthreads();
    unsigned int T16;
    {
        int m = wsum[0][0];
#pragma unroll
        for (int w = 1; w < 8; ++w) m = min(m, wsum[0][w]);
        T16 = (unsigned int)m;
    }

    // C: ballot-compaction of candidate indices (cap 512) + exact fallback.
    int nval;
    for (int attempt = 0;; ++attempt) {
        if (t == 0) s_cnt = 0;
        __syncthreads();
        int wtot = 0;
#pragma unroll
        for (int i = 0; i < NV9; ++i) {
            wtot += __popcll(__ballot((u2[i] & 0xFFFFu) >= T16));
            wtot += __popcll(__ballot((u2[i] >> 16) >= T16));
        }
        int wbase = 0;
        if (lane == 0) wbase = atomicAdd(&s_cnt, wtot);
        wbase = __shfl(wbase, 0);
        int run = wbase;
#pragma unroll
        for (int i = 0; i < NV9; ++i) {
#pragma unroll
            for (int h = 0; h < 2; ++h) {
                unsigned int bits16 = h ? (u2[i] >> 16) : (u2[i] & 0xFFFFu);
                bool pred = (bits16 >= T16);
                ull bal = __ballot(pred);
                if (pred) {
                    int slot = run + __popcll(bal & lmask_lt);
                    if (slot < 2 * KPRE)
                        arr[slot] = (ull)(unsigned int)((((i << 9) + t) << 1) + h);
                }
                run += __popcll(bal);
            }
        }
        __syncthreads();
        if (s_cnt <= 2 * KPRE || attempt == 1) { nval = min(s_cnt, 2 * KPRE); break; }
        unsigned int lo = T16, hi = T16_HI;
        int it = 0;
        while (hi - lo > 1u) {
            unsigned int mid = lo + ((hi - lo) >> 1);
            int cc = 0;
#pragma unroll
            for (int i = 0; i < NV9; ++i) {
                cc += __popcll(__ballot((u2[i] & 0xFFFFu) >= mid));
                cc += __popcll(__ballot((u2[i] >> 16) >= mid));
            }
            if (lane == 0) wsum[it & 1][wid] = cc;
            __syncthreads();
            int totc = 0;
#pragma unroll
            for (int w = 0; w < 8; ++w) totc += wsum[it & 1][w];
            if (totc >= KPRE) lo = mid; else hi = mid;
            ++it;
        }
        T16 = lo;
    }

    if (t >= nval) arr[t] = (ull)0xFFFFFFFFu;   // sentinel index (invalid)
    __syncthreads();

    // C2: gather exact fp32 score for MY candidate slot (1/thread).
    // UNSIGNED bounds guard (R11 lesson: sentinel -1 must be invalid).
    const float* cb = conf + (size_t)b * P * NUM_CLASSES + (c + 1);
    const float2* nb = norm + (size_t)b * P;
    ull k0;
    {
        unsigned int pa = (unsigned int)arr[t];
        if (pa < (unsigned int)P) {
            float xa = cb[(size_t)pa * NUM_CLASSES];
            float2 ma = nb[pa];
            float v = expf(xa - ma.x) / ma.y;
            k0 = ((ull)__float_as_uint(v) << 32) | (unsigned int)(~pa);
        } else {
            k0 = 0ULL;
        }
    }
    __syncthreads();

    // D: 512-wide bitonic sort, ONE key/thread, descending.
    {
        int lstage = 0;
#pragma unroll
        for (int kk = 2; kk <= 2 * KPRE; kk <<= 1) {
#pragma unroll
            for (int j = kk >> 1; j > 0; j >>= 1) {
                bool amLow = ((t & j) == 0);
                bool d0 = ((t & kk) == 0);
                if (j >= 64) {
                    ull* A = (lstage & 1) ? arr : arr2;
                    ++lstage;
                    A[t] = k0;
                    __syncthreads();
                    ull o0 = A[t ^ j];
                    k0 = (d0 == amLow) ? ((k0 > o0) ? k0 : o0) : ((k0 > o0) ? o0 : k0);
                } else {
                    ull o0 = __shfl_xor(k0, j);
                    k0 = (d0 == amLow) ? ((k0 > o0) ? k0 : o0) : ((k0 > o0) ? o0 : k0);
                }
            }
        }
    }
    const ull key = k0;    // threads 0..255 hold the top-256, sorted descending

    // E: decode candidate t (threads < 256 only)
    float v = 0.f, x1 = 0.f, y1 = 0.f, x2 = 0.f, y2 = 0.f;
    if (t < KPRE) {
        v = __uint_as_float((unsigned int)(key >> 32));
        int idx = (int)(~(unsigned int)(key & 0xFFFFFFFFu));
        if (idx < 0 || idx >= P) { idx = 0; v = 0.f; }

        const float4 lv = *(const float4*)(loc + ((size_t)b * P + idx) * 4);
        const float4 pv = *(const float4*)(prior + (size_t)idx * 4);
        float cx = pv.x + (lv.x * VAR0) * pv.z;
        float cy = pv.y + (lv.y * VAR0) * pv.w;
        float w = pv.z * expf(lv.z * VAR1);
        float h = pv.w * expf(lv.w * VAR1);
        x1 = cx - w * 0.5f;
        y1 = cy - h * 0.5f;
        x2 = x1 + w;
        y2 = y1 + h;
        float myarea = fmaxf(x2 - x1, 0.f) * fmaxf(y2 - y1, 0.f);
        sbox[BSLOT(t)] = make_float4(x1, y1, x2, y2);
        sarea[BSLOT(t)] = myarea;
    }
    __syncthreads();

    // F1: balanced mask build (640 (row,tile) pairs over 512 threads, max 2)
#pragma unroll
    for (int rep = 0; rep < 2; ++rep) {
        int pid = t + (rep << 9);
        if (pid < 640) {
            int r, w2;
            if (pid < 64)       { r = pid;                w2 = 0; }
            else if (pid < 192) { int q = pid - 64;  r = 64  + (q >> 1); w2 = q & 1; }
            else if (pid < 384) { int q = pid - 192; int q3 = q / 3; r = 128 + q3; w2 = q - 3 * q3; }
            else                { int q = pid - 384; r = 192 + (q >> 2); w2 = q & 3; }
            float4 rb = sbox[BSLOT(r)];
            float ra = sarea[BSLOT(r)];
            ull mm = 0ULL;
            for (int i = 0; i < 64; ++i) {
                int gg = (w2 << 6) + i;
                float4 gb = sbox[BSLOT(gg)];
                float lx = fmaxf(gb.x, rb.x), ly = fmaxf(gb.y, rb.y);
                float rx = fminf(gb.z, rb.z), ry = fminf(gb.w, rb.w);
                float iw = fmaxf(rx - lx, 0.f), ih = fmaxf(ry - ly, 0.f);
                float inter = iw * ih;
                float uni = sarea[BSLOT(gg)] + ra - inter;
                bool s = (inter / fmaxf(uni, 1e-9f)) > NMS_TH;
                mm |= ((ull)(s ? 1u : 0u)) << i;
            }
            smask[r][w2] = mm;
        }
    }
    __syncthreads();

    // F2: waves 0..3 resolve (t < 256); waves 4..7 just pass the barriers.
    ull m0 = 0ULL, m1 = 0ULL, m2 = 0ULL, m3 = 0ULL;
    if (t < KPRE) {
        m0 = smask[t][0];
        m1 = (wid >= 1) ? smask[t][1] : 0ULL;
        m2 = (wid >= 2) ? smask[t][2] : 0ULL;
        m3 = (wid >= 3) ? smask[t][3] : 0ULL;
        if (wid == 0) m0 &= lmask_lt;
        else if (wid == 1) m1 &= lmask_lt;
        else if (wid == 2) m2 &= lmask_lt;
        else m3 &= lmask_lt;
    }

    int alive = (t < KPRE && v > CONF_TH) ? 1 : 0;
    ull mykept = 0ULL;
#pragma unroll
    for (int w2 = 0; w2 < 4; ++w2) {
        if (wid == w2) {          // only true for t < 256
            if (w2 > 0 && (m0 & kept_mask[0])) alive = 0;
            if (w2 > 1 && (m1 & kept_mask[1])) alive = 0;
            if (w2 > 2 && (m2 & kept_mask[2])) alive = 0;
            ull mw = (w2 == 0) ? m0 : (w2 == 1) ? m1 : (w2 == 2) ? m2 : m3;
            ull validb = __ballot(alive != 0);
            ull todo = __ballot((mw & validb) != 0ULL) & validb;
            ull kept = validb & ~todo;
            while (todo) {
                int i = __builtin_ctzll(todo);
                ull row = __shfl(mw, i);
                if ((row & kept) == 0ULL) kept |= (1ULL << i);
                todo &= (todo - 1ULL);
            }
            mykept = kept;
            alive = (int)((kept >> lane) & 1ULL);
            if (lane == 0) kept_mask[w2] = kept;
        }
        __syncthreads();
    }

    // G: rank via popcounts, write kept rows + zero-fill (t < 256 relevant)
    int rank = 0;
#pragma unroll
    for (int w2 = 0; w2 < 4; ++w2)
        if (w2 < wid) rank += __popcll(kept_mask[w2]);
    rank += __popcll(mykept & lmask_lt);
    int total = 0;
#pragma unroll
    for (int w2 = 0; w2 < 4; ++w2) total += __popcll(kept_mask[w2]);

    float* orow = out + (size_t)pair * TOPK * 5;
    if (alive && rank < TOPK) {
        float* o = orow + rank * 5;
        o[0] = v; o[1] = x1; o[2] = y1; o[3] = x2; o[4] = y2;
    }
    if (t < TOPK && t >= total) {
        float* o = orow + t * 5;
        o[0] = 0.f; o[1] = 0.f; o[2] = 0.f; o[3] = 0.f; o[4] = 0.f;
    }
}

extern "C" void kernel_launch(void* const* d_in, const int* in_sizes, int n_in,
                              void* d_out, int out_size, void* d_ws, size_t ws_size,
                              hipStream_t stream) {
    const float* loc = (const float*)d_in[0];
    const float* conf = (const float*)d_in[1];
    const float* prior = (const float*)d_in[2];
    float* out = (float*)d_out;

    int P = in_sizes[2] / 4;                // 8732
    int B = in_sizes[0] / (4 * P);          // 32
    int nch = (P + 255) / 256;              // 35

    float2* norm = (float2*)d_ws;                                   // 2.23 MB
    ushort* probs16 = (ushort*)((char*)d_ws + (size_t)B * P * 8);   // 11.17 MB (16B-aligned)

    rownorm16_kernel<<<dim3(B * nch), 256, 0, stream>>>(conf, norm, probs16, B, P);
    nms_topk_kernel<<<B * NFG, NTHR, 0, stream>>>(conf, norm, probs16, loc, prior, out, B, P);
}

// Round 15
// 119.566 us; speedup vs baseline: 2.5013x; 1.0213x over previous
//
#include <hip/hip_runtime.h>
#include <stdint.h>

typedef unsigned long long ull;
typedef float f4v __attribute__((ext_vector_type(4)));

#define NUM_CLASSES 21
#define NFG 20
#define TOPK 200
#define KPRE 256
#define NTHR 512                 // nms block size (8 waves)
#define CONF_TH 0.01f
#define NMS_TH 0.45f
#define VAR0 0.1f
#define VAR1 0.2f
#define NV9 9                    // ceil((8732/2)/512) uint regs (2 u16 scores each)
#define T16_LO 0x3C23u           // __float_as_uint(0.01f)>>16 (~0.00995 floor)
#define T16_HI 0x3F81u           // just above 1.0f in top-16 bits
// skewed LDS slot: g, g+64, g+128, g+192 land in different banks
#define BSLOT(g) ((g) + ((g) >> 6))

// Kernel 1: unchanged from R14 (verified). Per-row softmax normalizers (mx,s)
// + truncated u16 scores, transposed [B][NFG][P] (13.4 MB), agent-scope stores.
__global__ __launch_bounds__(256) void rownorm16_kernel(
    const float* __restrict__ conf, float2* __restrict__ norm,
    ushort* __restrict__ probs16, int B, int P) {
    __shared__ __align__(16) float buf[256 * NUM_CLASSES];   // 21504 B
    __shared__ __align__(16) ushort b16[NFG * 256];          // 10240 B transpose
    const int t = threadIdx.x;
    const int nch = (P + 255) >> 8;              // 35

    const int id = blockIdx.x;
    int b, chk;
    if ((B & 7) == 0) {
        int r = id & 7, m = id >> 3;
        int q = m / nch;
        b = r + (q << 3);
        chk = m - q * nch;
    } else {
        b = id / nch;
        chk = id - b * nch;
    }
    const int p0 = chk << 8;
    const int cnt = min(256, P - p0);
    const float* src = conf + ((size_t)b * P + p0) * NUM_CLASSES;  // 16B aligned

    if (cnt == 256) {
        const f4v* s4 = (const f4v*)src;
        f4v* b4 = (f4v*)buf;
#pragma unroll
        for (int k = 0; k < 6; ++k) {
            int i = (k << 8) + t;
            if (i < (256 * NUM_CLASSES) / 4) b4[i] = s4[i];
        }
    } else {
        int n = cnt * NUM_CLASSES;
        for (int i = t; i < n; i += 256) buf[i] = src[i];
    }
    __syncthreads();

    if (t < cnt) {
        const float* row = buf + t * NUM_CLASSES;   // stride 21 => 2-way (free)
        float x[NUM_CLASSES];
        float mx = row[0];
        x[0] = mx;
#pragma unroll
        for (int j = 1; j < NUM_CLASSES; ++j) { x[j] = row[j]; mx = fmaxf(mx, x[j]); }
        float s = 0.f;
#pragma unroll
        for (int j = 0; j < NUM_CLASSES; ++j) { x[j] = expf(x[j] - mx); s += x[j]; }
        ull nv = (ull)__float_as_uint(mx) | ((ull)__float_as_uint(s) << 32);
        __hip_atomic_store((ull*)(norm + (size_t)b * P + p0 + t), nv,
                           __ATOMIC_RELAXED, __HIP_MEMORY_SCOPE_AGENT);
#pragma unroll
        for (int c = 1; c < NUM_CLASSES; ++c) {
            float v = x[c] / s;                     // true IEEE div (exact score)
            b16[(c - 1) * 256 + t] = (ushort)(__float_as_uint(v) >> 16);
        }
    }
    __syncthreads();

    if (cnt == 256) {
        const uint* s32 = (const uint*)b16;
#pragma unroll
        for (int k = 0; k < 10; ++k) {
            int e = (k << 8) + t;
            int c = e >> 7;
            int q = e & 127;
            uint* dstu = (uint*)(probs16 + ((size_t)b * NFG + c) * P + p0);
            __hip_atomic_store(dstu + q, s32[(c << 7) + q],
                               __ATOMIC_RELAXED, __HIP_MEMORY_SCOPE_AGENT);
        }
    } else {
        for (int e = t; e < NFG * cnt; e += 256) {
            int c = e / cnt;
            int f = e - c * cnt;
            __hip_atomic_store(probs16 + ((size_t)b * NFG + c) * P + p0 + f,
                               b16[c * 256 + f],
                               __ATOMIC_RELAXED, __HIP_MEMORY_SCOPE_AGENT);
        }
    }
}

// Kernel 2: one block per (b, fg_class), 512 threads. R14 profile: all 640
// blocks co-resident (capacity 4/CU) => VALU-throughput bound. This round:
// (1) F1 rebuilt wave-per-w2-strip: gb loaded once per strip, rb via LDS
//     broadcast, mask via ONE __ballot — removes the 64-iter serial
//     mask-build and the scattered LDS reads;
// (2) EXACT div-free IoU predicate: RN(inter/u) > 0.45f <=> inter > M*u
//     (reals), M = midpoint(0.45f, succ(0.45f)) = 30198989/2^26; the double
//     product M*(double)u is exact (25+24 bits < 53); tie inter==M*u rounds
//     to even = 0.45f => ref false = our strict '>' false. Bit-exact.
// (3) u16 lo/hi pre-split (removes and/shift from every B/C compare).
__global__ __launch_bounds__(NTHR) void nms_topk_kernel(
    const float* __restrict__ conf, const float2* __restrict__ norm,
    const ushort* __restrict__ probs16, const float* __restrict__ loc,
    const float* __restrict__ prior, float* __restrict__ out, int B, int P) {

    __shared__ ull arr[2 * KPRE];               // 512 sort keys
    __shared__ ull arr2[2 * KPRE];              // double buffer for sort LDS stages
    __shared__ int wsum[2][8];
    __shared__ int s_cnt;
    __shared__ float4 sbox[KPRE + (KPRE >> 6)]; // skewed (BSLOT)
    __shared__ float sarea[KPRE + (KPRE >> 6)];
    __shared__ ull smask[KPRE][5];              // padded stride 40B: 2-way (free)
    __shared__ ull kept_mask[4];

    const int t = threadIdx.x;
    const int lane = t & 63;
    const int wid = t >> 6;                     // 0..7
    const ull lmask_lt = (1ULL << lane) - 1ULL;

    const int g = blockIdx.x;
    int b, c;
    if ((B & 7) == 0) {
        int k = g >> 3;
        b = ((k / NFG) << 3) + (g & 7);
        c = k - (k / NFG) * NFG;
    } else {
        b = g / NFG;
        c = g - (g / NFG) * NFG;
    }
    const int pair = b * NFG + c;
    const int nq = P >> 1;                      // 4366 uints (P even)

    // A: u16 scores, pre-split into lo/hi halves (saves an and/shift on
    // every compare in B and C).
    unsigned int lo16[NV9], hi16[NV9];
    {
        const uint* sp16 = (const uint*)(probs16 + (size_t)pair * P);
#pragma unroll
        for (int i = 0; i < NV9; ++i) {
            int q = (i << 9) + t;
            unsigned int u = (q < nq) ? sp16[q] : 0u;   // 0 => never >= T16
            lo16[i] = u & 0xFFFFu;
            hi16[i] = u >> 16;
        }
    }
    // score reg (i,h) corresponds to prior p = (((i<<9)+t)<<1)+h

    // B: WAVE-LOCAL coarse binary search on u16 (10 iters, no barriers).
    // Per-wave target = KPRE/8 = 32; global T16 = min of 8 wave thresholds.
    {
        unsigned int lo = T16_LO, hi = T16_HI;
        while (hi - lo > 1u) {
            unsigned int mid = lo + ((hi - lo) >> 1);
            int cc = 0;
#pragma unroll
            for (int i = 0; i < NV9; ++i) {
                cc += __popcll(__ballot(lo16[i] >= mid));
                cc += __popcll(__ballot(hi16[i] >= mid));
            }
            if (cc >= KPRE / 8) lo = mid; else hi = mid;
        }
        if (lane == 0) wsum[0][wid] = (int)lo;
    }
    __syncthreads();
    unsigned int T16;
    {
        int m = wsum[0][0];
#pragma unroll
        for (int w = 1; w < 8; ++w) m = min(m, wsum[0][w]);
        T16 = (unsigned int)m;
    }

    // C: ballot-compaction of candidate indices (cap 512) + exact fallback.
    int nval;
    for (int attempt = 0;; ++attempt) {
        if (t == 0) s_cnt = 0;
        __syncthreads();
        int wtot = 0;
#pragma unroll
        for (int i = 0; i < NV9; ++i) {
            wtot += __popcll(__ballot(lo16[i] >= T16));
            wtot += __popcll(__ballot(hi16[i] >= T16));
        }
        int wbase = 0;
        if (lane == 0) wbase = atomicAdd(&s_cnt, wtot);
        wbase = __shfl(wbase, 0);
        int run = wbase;
#pragma unroll
        for (int i = 0; i < NV9; ++i) {
#pragma unroll
            for (int h = 0; h < 2; ++h) {
                unsigned int bits16 = h ? hi16[i] : lo16[i];
                bool pred = (bits16 >= T16);
                ull bal = __ballot(pred);
                if (pred) {
                    int slot = run + __popcll(bal & lmask_lt);
                    if (slot < 2 * KPRE)
                        arr[slot] = (ull)(unsigned int)((((i << 9) + t) << 1) + h);
                }
                run += __popcll(bal);
            }
        }
        __syncthreads();
        if (s_cnt <= 2 * KPRE || attempt == 1) { nval = min(s_cnt, 2 * KPRE); break; }
        unsigned int lo = T16, hi = T16_HI;
        int it = 0;
        while (hi - lo > 1u) {
            unsigned int mid = lo + ((hi - lo) >> 1);
            int cc = 0;
#pragma unroll
            for (int i = 0; i < NV9; ++i) {
                cc += __popcll(__ballot(lo16[i] >= mid));
                cc += __popcll(__ballot(hi16[i] >= mid));
            }
            if (lane == 0) wsum[it & 1][wid] = cc;
            __syncthreads();
            int totc = 0;
#pragma unroll
            for (int w = 0; w < 8; ++w) totc += wsum[it & 1][w];
            if (totc >= KPRE) lo = mid; else hi = mid;
            ++it;
        }
        T16 = lo;
    }

    if (t >= nval) arr[t] = (ull)0xFFFFFFFFu;   // sentinel index (invalid)
    __syncthreads();

    // C2: gather exact fp32 score for MY candidate slot (1/thread).
    // UNSIGNED bounds guard (R11 lesson: sentinel -1 must be invalid).
    const float* cb = conf + (size_t)b * P * NUM_CLASSES + (c + 1);
    const float2* nb = norm + (size_t)b * P;
    ull k0;
    {
        unsigned int pa = (unsigned int)arr[t];
        if (pa < (unsigned int)P) {
            float xa = cb[(size_t)pa * NUM_CLASSES];
            float2 ma = nb[pa];
            float v = expf(xa - ma.x) / ma.y;
            k0 = ((ull)__float_as_uint(v) << 32) | (unsigned int)(~pa);
        } else {
            k0 = 0ULL;
        }
    }
    __syncthreads();

    // D: 512-wide bitonic sort, ONE key/thread, descending.
    // key = (bits<<32)|~idx => value desc, index asc (JAX tie-break).
    {
        int lstage = 0;
#pragma unroll
        for (int kk = 2; kk <= 2 * KPRE; kk <<= 1) {
#pragma unroll
            for (int j = kk >> 1; j > 0; j >>= 1) {
                bool amLow = ((t & j) == 0);
                bool d0 = ((t & kk) == 0);
                if (j >= 64) {
                    ull* A = (lstage & 1) ? arr : arr2;
                    ++lstage;
                    A[t] = k0;
                    __syncthreads();
                    ull o0 = A[t ^ j];
                    k0 = (d0 == amLow) ? ((k0 > o0) ? k0 : o0) : ((k0 > o0) ? o0 : k0);
                } else {
                    ull o0 = __shfl_xor(k0, j);
                    k0 = (d0 == amLow) ? ((k0 > o0) ? k0 : o0) : ((k0 > o0) ? o0 : k0);
                }
            }
        }
    }
    const ull key = k0;    // threads 0..255 hold the top-256, sorted descending

    // E: decode candidate t (threads < 256 only)
    float v = 0.f, x1 = 0.f, y1 = 0.f, x2 = 0.f, y2 = 0.f;
    if (t < KPRE) {
        v = __uint_as_float((unsigned int)(key >> 32));
        int idx = (int)(~(unsigned int)(key & 0xFFFFFFFFu));
        if (idx < 0 || idx >= P) { idx = 0; v = 0.f; }

        const float4 lv = *(const float4*)(loc + ((size_t)b * P + idx) * 4);
        const float4 pv = *(const float4*)(prior + (size_t)idx * 4);
        float cx = pv.x + (lv.x * VAR0) * pv.z;
        float cy = pv.y + (lv.y * VAR0) * pv.w;
        float w = pv.z * expf(lv.z * VAR1);
        float h = pv.w * expf(lv.w * VAR1);
        x1 = cx - w * 0.5f;
        y1 = cy - h * 0.5f;
        x2 = x1 + w;
        y2 = y1 + h;
        float myarea = fmaxf(x2 - x1, 0.f) * fmaxf(y2 - y1, 0.f);
        sbox[BSLOT(t)] = make_float4(x1, y1, x2, y2);
        sarea[BSLOT(t)] = myarea;
    }
    __syncthreads();

    // F1: wave-per-w2-strip mask build. For each column strip w2, each lane
    // holds ONE column box (loaded once); rows are walked wave-uniformly
    // (rb/ra are LDS broadcasts) and the 64-bit suppression mask comes from
    // a single ballot. Covers exactly {(r,w2): w2 <= r>>6}: 80 rows/wave.
    // Predicate: exact div-free form of RN(inter/u) > 0.45f (see header).
    {
        const double Mth = 30198989.0 / 67108864.0;   // midpoint(0.45f, succ)
#pragma unroll
        for (int w2 = 0; w2 < 4; ++w2) {
            int gg = (w2 << 6) + lane;
            float4 gb = sbox[BSLOT(gg)];
            float ga = sarea[BSLOT(gg)];
            for (int r = (w2 << 6) + wid; r < KPRE; r += 8) {
                float4 rb = sbox[BSLOT(r)];     // wave-uniform -> broadcast
                float ra = sarea[BSLOT(r)];
                float lx = fmaxf(gb.x, rb.x), ly = fmaxf(gb.y, rb.y);
                float rx = fminf(gb.z, rb.z), ry = fminf(gb.w, rb.w);
                float iw = fmaxf(rx - lx, 0.f), ih = fmaxf(ry - ly, 0.f);
                float inter = iw * ih;
                float uni = fmaxf(ga + ra - inter, 1e-9f);
                bool s = ((double)inter > Mth * (double)uni);
                ull bal = __ballot(s);
                if (lane == 0) smask[r][w2] = bal;
            }
        }
    }
    __syncthreads();

    // F2: waves 0..3 resolve (t < 256); waves 4..7 just pass the barriers.
    ull m0 = 0ULL, m1 = 0ULL, m2 = 0ULL, m3 = 0ULL;
    if (t < KPRE) {
        m0 = smask[t][0];
        m1 = (wid >= 1) ? smask[t][1] : 0ULL;
        m2 = (wid >= 2) ? smask[t][2] : 0ULL;
        m3 = (wid >= 3) ? smask[t][3] : 0ULL;
        if (wid == 0) m0 &= lmask_lt;
        else if (wid == 1) m1 &= lmask_lt;
        else if (wid == 2) m2 &= lmask_lt;
        else m3 &= lmask_lt;
    }

    int alive = (t < KPRE && v > CONF_TH) ? 1 : 0;
    ull mykept = 0ULL;
#pragma unroll
    for (int w2 = 0; w2 < 4; ++w2) {
        if (wid == w2) {          // only true for t < 256
            if (w2 > 0 && (m0 & kept_mask[0])) alive = 0;
            if (w2 > 1 && (m1 & kept_mask[1])) alive = 0;
            if (w2 > 2 && (m2 & kept_mask[2])) alive = 0;
            ull mw = (w2 == 0) ? m0 : (w2 == 1) ? m1 : (w2 == 2) ? m2 : m3;
            ull validb = __ballot(alive != 0);
            ull todo = __ballot((mw & validb) != 0ULL) & validb;
            ull kept = validb & ~todo;
            while (todo) {
                int i = __builtin_ctzll(todo);
                ull row = __shfl(mw, i);
                if ((row & kept) == 0ULL) kept |= (1ULL << i);
                todo &= (todo - 1ULL);
            }
            mykept = kept;
            alive = (int)((kept >> lane) & 1ULL);
            if (lane == 0) kept_mask[w2] = kept;
        }
        __syncthreads();
    }

    // G: rank via popcounts, write kept rows + zero-fill (t < 256 relevant)
    int rank = 0;
#pragma unroll
    for (int w2 = 0; w2 < 4; ++w2)
        if (w2 < wid) rank += __popcll(kept_mask[w2]);
    rank += __popcll(mykept & lmask_lt);
    int total = 0;
#pragma unroll
    for (int w2 = 0; w2 < 4; ++w2) total += __popcll(kept_mask[w2]);

    float* orow = out + (size_t)pair * TOPK * 5;
    if (alive && rank < TOPK) {
        float* o = orow + rank * 5;
        o[0] = v; o[1] = x1; o[2] = y1; o[3] = x2; o[4] = y2;
    }
    if (t < TOPK && t >= total) {
        float* o = orow + t * 5;
        o[0] = 0.f; o[1] = 0.f; o[2] = 0.f; o[3] = 0.f; o[4] = 0.f;
    }
}

extern "C" void kernel_launch(void* const* d_in, const int* in_sizes, int n_in,
                              void* d_out, int out_size, void* d_ws, size_t ws_size,
                              hipStream_t stream) {
    const float* loc = (const float*)d_in[0];
    const float* conf = (const float*)d_in[1];
    const float* prior = (const float*)d_in[2];
    float* out = (float*)d_out;

    int P = in_sizes[2] / 4;                // 8732
    int B = in_sizes[0] / (4 * P);          // 32
    int nch = (P + 255) / 256;              // 35

    float2* norm = (float2*)d_ws;                                   // 2.23 MB
    ushort* probs16 = (ushort*)((char*)d_ws + (size_t)B * P * 8);   // 11.17 MB (16B-aligned)

    rownorm16_kernel<<<dim3(B * nch), 256, 0, stream>>>(conf, norm, probs16, B, P);
    nms_topk_kernel<<<B * NFG, NTHR, 0, stream>>>(conf, norm, probs16, loc, prior, out, B, P);
}